// Round 10
// baseline (1205.375 us; speedup 1.0000x reference)
//
#include <hip/hip_runtime.h>
#include <math.h>

// ---------------------------------------------------------------------------
// VQ-VAE forward. Round 17: R16 showed conv2 is latency/barrier-paced (all
// pipes idle: Mfma 20%, VALU 14%, HBM 6%; conflicts identical across two
// different A-paths -> not binding). Fixes, conv template only:
//  (a) depth-2 input prefetch (2 named pfa sets, loop unrolled x2): chunk
//      loads get ~2 compute phases of latency cover instead of 1.
//  (b) epilogue buffer [NB][68] -> [NB][36] via two m-half passes: SMEM
//      drops 34.8K -> ~24.7K (conv2) raising blocks/CU 4 -> 6.
// Numerics bit-identical. convT/conv1/quantizer unchanged from passing R16.
// ---------------------------------------------------------------------------

typedef __attribute__((ext_vector_type(8))) short bf16x8;
typedef __attribute__((ext_vector_type(4))) float f32x4;
union FragU { unsigned u[4]; bf16x8 v; };

__device__ __forceinline__ unsigned bf16_rne(unsigned u) {
    return (u + 0x7FFFu + ((u >> 16) & 1u)) >> 16;
}
// pack fp32 -> u32: low16 = bf16(v), high16 = bf16(v - bf16(v))
__device__ __forceinline__ unsigned pack_split(float v) {
    unsigned u = __builtin_bit_cast(unsigned, v);
    unsigned hi = bf16_rne(u);
    float hif = __builtin_bit_cast(float, hi << 16);
    float r = v - hif;
    unsigned lo = bf16_rne(__builtin_bit_cast(unsigned, r));
    return hi | (lo << 16);
}

__global__ void __launch_bounds__(256) pack_tensor(
    const float* __restrict__ s, unsigned* __restrict__ d, int n)
{
    int i = blockIdx.x * 256 + threadIdx.x;
    if (i < n) d[i] = pack_split(s[i]);
}

// conv1 weights (64,3,4,4) -> padded packed [64][64] (k>=48 zero)
__global__ void __launch_bounds__(256) pack_w1(
    const float* __restrict__ w, unsigned* __restrict__ wq)
{
    int idx = blockIdx.x * 256 + threadIdx.x;
    if (idx >= 64 * 64) return;
    int k = idx & 63, oc = idx >> 6;
    float v = (k < 48) ? w[oc * 48 + k] : 0.0f;
    wq[idx] = pack_split(v);
}

// encoder weights (Cout, K) -> pair-planes [2][Cout][K/2]:
// plane0[oc][kp] = (hi(k=2kp) | hi(2kp+1)<<16), plane1 = lo halves.
template<int Cout, int K>
__global__ void __launch_bounds__(256) pack_w_planes(
    const float* __restrict__ w, unsigned* __restrict__ wq)
{
    constexpr int K2 = K / 2;
    constexpr int TOT = Cout * K;           // u32 outputs over both planes
    int idx = blockIdx.x * 256 + threadIdx.x;
    if (idx >= TOT) return;
    int kp   = idx % K2;
    int rest = idx / K2;
    int oc   = rest % Cout;
    int p    = rest / Cout;
    unsigned u0 = pack_split(w[(size_t)oc * K + 2 * kp]);
    unsigned u1 = pack_split(w[(size_t)oc * K + 2 * kp + 1]);
    wq[idx] = (p == 0) ? ((u0 & 0xffffu) | (u1 << 16))
                       : ((u0 >> 16) | (u1 & 0xffff0000u));
}

// ConvTranspose weights (torch Cin,Cout,4,4) -> pair-planes
// [2][par][Cout][K/2], K = Cin*4, k = ci*4 + (2r+s), par = dy*2+dx.
template<int Cin, int Cout>
__global__ void __launch_bounds__(256) repack_wt_planes(
    const float* __restrict__ w, unsigned* __restrict__ wq)
{
    constexpr int K = Cin * 4, K2 = K / 2;
    constexpr int TOT = 2 * 4 * Cout * K2;
    int idx = blockIdx.x * 256 + threadIdx.x;
    if (idx >= TOT) return;
    int kp   = idx % K2;
    int rest = idx / K2;
    int co   = rest % Cout;
    rest    /= Cout;
    int par  = rest & 3;
    int p    = rest >> 2;
    int dy = par >> 1, dx = par & 1;
    unsigned u01[2];
#pragma unroll
    for (int e = 0; e < 2; ++e) {
        int k = 2 * kp + e;
        int t = k & 3, ci = k >> 2;
        int r = t >> 1, s = t & 1;
        int ky = 3 - dy - 2 * r;
        int kx = 3 - dx - 2 * s;
        u01[e] = pack_split(w[(((size_t)ci * Cout + co) * 4 + ky) * 4 + kx]);
    }
    wq[idx] = (p == 0) ? ((u01[0] & 0xffffu) | (u01[1] << 16))
                       : ((u01[0] >> 16) | (u01[1] & 0xffff0000u));
}

// transpose codebook: embed[1024][512] -> et[512][1024]
__global__ void __launch_bounds__(256) embed_transpose(
    const float* __restrict__ embed, float* __restrict__ et)
{
    int idx = blockIdx.x * 256 + threadIdx.x;
    int c = idx & 1023, k = idx >> 10;
    et[idx] = embed[(size_t)c * 512 + k];
}

// ================= MFMA conv k=4 s=2 p=1 + ReLU (implicit GEMM) ============
// hi/lo u16-plane A staging (R16) + depth-2 input prefetch + half epilogue.
template<int Cin, int H, int W, int Cout, int NB, int PACKO>
__global__ void __launch_bounds__(256) conv4s2_mfma(
    const unsigned* __restrict__ xp, const unsigned* __restrict__ wp,
    const float* __restrict__ bias, float* __restrict__ y)
{
    constexpr int OH = H / 2, OW = W / 2;
    constexpr int LOG_OW = (OW == 64) ? 6 : (OW == 32) ? 5 : 4;
    constexpr int R   = 64 / OW;
    constexpr int RT  = 2 * R + 2;
    constexpr int CS  = W + 2;              // staged cols (halo)
    constexpr int CS2 = CS + 2;             // u16 LDS row stride (even)
    constexpr int XEL = 2 * RT * CS;
    constexpr int XIT = (XEL + 255) / 256;
    constexpr int K   = Cin * 16;
    constexpr int K2  = K / 2;
    constexpr int NC  = Cin / 2;            // even for all layers
    constexpr int NT  = NB / 64;
    constexpr int WR  = NB / 16;            // weight rows per plane
    constexpr int WIT = NB / 8;
    constexpr int MBC = 32 * OH * OW / 64;
    constexpr int RAWU = RT * CS2;          // u32 per u16 plane (2 channels)
    constexpr int OFF_RL = RAWU;
    constexpr int OFF_WH = ((2 * RAWU) + 7) & ~7;
    constexpr int OFF_WL = OFF_WH + NB * 20;
    constexpr int SM1 = OFF_WL + NB * 20;
    constexpr int SM2 = NB * 36;            // half epilogue buffer
    constexpr int SMEM = SM1 > SM2 ? SM1 : SM2;

    __shared__ unsigned smem[SMEM];
    unsigned short* rawh = (unsigned short*)smem;
    unsigned short* rawl = (unsigned short*)(smem + OFF_RL);
    unsigned* wbh = smem + OFF_WH;
    unsigned* wbl = smem + OFF_WL;

    int bid = blockIdx.x;
    int mb = bid % MBC, ng = bid / MBC;
    int oc0 = ng * NB;
    int m0 = mb * 64;
    int nimg = m0 / (OH * OW);
    int sp0 = m0 % (OH * OW);
    int oyb = sp0 >> LOG_OW;

    int tid  = threadIdx.x;
    int lane = tid & 63, wv = tid >> 6;
    int lm = lane & 15, q = lane >> 4;
    int n0w = wv * 16 * NT;

    const unsigned* xbase = xp + (size_t)nimg * Cin * H * W;

    int  goff[XIT];
    bool gok[XIT];
    int  sidx[XIT];
#pragma unroll
    for (int s = 0; s < XIT; ++s) {
        int i = tid + 256 * s;
        goff[s] = 0; gok[s] = false; sidx[s] = 0;
        if (i < XEL) {
            int lc = i % CS;
            int t2 = i / CS;
            int lr = t2 % RT;
            int c  = t2 / RT;
            int gr = 2 * oyb - 1 + lr;
            int gc = lc - 1;
            bool ok = ((unsigned)gr < (unsigned)H) && ((unsigned)gc < (unsigned)W);
            goff[s] = ok ? (c * H * W + gr * W + gc) : 0;
            gok[s]  = ok;
            sidx[s] = (c * RT + lr) * CS2 + lc;
        }
    }
    // B loader: row = tid>>4 (16 oc at a time), kp col = tid&15
    const unsigned* wbase_h = wp + (size_t)(oc0 + (tid >> 4)) * K2 + (tid & 15);
    const unsigned* wbase_l = wbase_h + (size_t)Cout * K2;
    int wlds0 = (tid >> 4) * 20 + (tid & 15);

    f32x4 acc[4][NT];
#pragma unroll
    for (int nt = 0; nt < NT; ++nt) {
        float b = bias[oc0 + n0w + nt * 16 + lm];
#pragma unroll
        for (int mt = 0; mt < 4; ++mt)
#pragma unroll
            for (int r = 0; r < 4; ++r) acc[mt][nt][r] = b;
    }

    unsigned pfa0[XIT], pfa1[XIT];
    unsigned pfb[WIT];

    auto load_a = [&](int ch, unsigned (&pfa)[XIT]) {
        const unsigned* cb = xbase + (size_t)(ch * 2) * (H * W);
#pragma unroll
        for (int s = 0; s < XIT; ++s) {
            unsigned v = 0;
            if (gok[s]) v = cb[goff[s]];
            pfa[s] = v;
        }
    };
    auto load_b = [&](int ch) {
        const unsigned* wch = wbase_h + ch * 16;
        const unsigned* wcl = wbase_l + ch * 16;
#pragma unroll
        for (int s = 0; s < WR; ++s) {
            pfb[2 * s]     = wch[(size_t)s * 16 * K2];
            pfb[2 * s + 1] = wcl[(size_t)s * 16 * K2];
        }
    };
    auto store_chunk = [&](unsigned (&pfa)[XIT]) {
#pragma unroll
        for (int s = 0; s < XIT; ++s) {
            int i = tid + 256 * s;
            if (i < XEL) {
                rawh[sidx[s]] = (unsigned short)(pfa[s] & 0xffffu);
                rawl[sidx[s]] = (unsigned short)(pfa[s] >> 16);
            }
        }
#pragma unroll
        for (int s = 0; s < WR; ++s) {
            wbh[wlds0 + s * 16 * 20] = pfb[2 * s];
            wbl[wlds0 + s * 16 * 20] = pfb[2 * s + 1];
        }
    };
    auto compute = [&]() {
        FragU bhi[NT], blo[NT];
#pragma unroll
        for (int nt = 0; nt < NT; ++nt) {
            int oc = n0w + nt * 16 + lm;
            uint4 th = *(const uint4*)&wbh[oc * 20 + q * 4];
            uint4 tl = *(const uint4*)&wbl[oc * 20 + q * 4];
            bhi[nt].u[0] = th.x; bhi[nt].u[1] = th.y;
            bhi[nt].u[2] = th.z; bhi[nt].u[3] = th.w;
            blo[nt].u[0] = tl.x; blo[nt].u[1] = tl.y;
            blo[nt].u[2] = tl.z; blo[nt].u[3] = tl.w;
        }
#pragma unroll
        for (int mt = 0; mt < 4; ++mt) {
            int m = mt * 16 + lm;
            int oyl = m >> LOG_OW, oxl = m & (OW - 1);
            int c = q >> 1, rb = 2 * oyl + (q & 1) * 2;
            int bidx = (c * RT + rb) * CS2 + 2 * oxl;   // even -> 4B aligned
            FragU ahi, alo;
            ahi.u[0] = *(const unsigned*)&rawh[bidx];
            ahi.u[1] = *(const unsigned*)&rawh[bidx + 2];
            ahi.u[2] = *(const unsigned*)&rawh[bidx + CS2];
            ahi.u[3] = *(const unsigned*)&rawh[bidx + CS2 + 2];
            alo.u[0] = *(const unsigned*)&rawl[bidx];
            alo.u[1] = *(const unsigned*)&rawl[bidx + 2];
            alo.u[2] = *(const unsigned*)&rawl[bidx + CS2];
            alo.u[3] = *(const unsigned*)&rawl[bidx + CS2 + 2];
#pragma unroll
            for (int nt = 0; nt < NT; ++nt) {
                acc[mt][nt] = __builtin_amdgcn_mfma_f32_16x16x32_bf16(
                    ahi.v, bhi[nt].v, acc[mt][nt], 0, 0, 0);
                acc[mt][nt] = __builtin_amdgcn_mfma_f32_16x16x32_bf16(
                    ahi.v, blo[nt].v, acc[mt][nt], 0, 0, 0);
                acc[mt][nt] = __builtin_amdgcn_mfma_f32_16x16x32_bf16(
                    alo.v, bhi[nt].v, acc[mt][nt], 0, 0, 0);
            }
        }
    };

    // prologue: chunk0 + chunk1 inputs, chunk0 weights
    load_a(0, pfa0);
    load_b(0);
    load_a(1, pfa1);
#pragma unroll 1
    for (int ch = 0; ch < NC; ch += 2) {
        // even chunk
        __syncthreads();
        store_chunk(pfa0);
        __syncthreads();
        load_b(ch + 1);                      // NC even -> always valid
        if (ch + 2 < NC) load_a(ch + 2, pfa0);
        compute();
        // odd chunk
        __syncthreads();
        store_chunk(pfa1);
        __syncthreads();
        if (ch + 2 < NC) load_b(ch + 2);
        if (ch + 3 < NC) load_a(ch + 3, pfa1);
        compute();
    }

    // ---- epilogue: two m-half passes through [NB][36] buffer ----
    float* cs = (float*)smem;
    constexpr int QT = 256 / NB;            // threads per channel
    constexpr int MH = 32 / QT;             // m per thread per pass
    int nl = tid / QT, qt = tid % QT;
#pragma unroll
    for (int p = 0; p < 2; ++p) {
        __syncthreads();
#pragma unroll
        for (int mh = 0; mh < 2; ++mh) {
            int mt = 2 * p + mh;
#pragma unroll
            for (int nt = 0; nt < NT; ++nt) {
                int nn = n0w + nt * 16 + lm;
#pragma unroll
                for (int r = 0; r < 4; ++r)
                    cs[nn * 36 + mh * 16 + q * 4 + r] = acc[mt][nt][r];
            }
        }
        __syncthreads();
        size_t gb = ((size_t)(nimg * Cout + oc0 + nl)) * (OH * OW)
                  + sp0 + p * 32 + qt * MH;
#pragma unroll
        for (int i2 = 0; i2 < MH / 4; ++i2) {
            float4 v = *(float4*)&cs[nl * 36 + qt * MH + 4 * i2];
            v.x = fmaxf(v.x, 0.0f); v.y = fmaxf(v.y, 0.0f);
            v.z = fmaxf(v.z, 0.0f); v.w = fmaxf(v.w, 0.0f);
            if (PACKO) {
                uint4 pk;
                pk.x = pack_split(v.x); pk.y = pack_split(v.y);
                pk.z = pack_split(v.z); pk.w = pack_split(v.w);
                *(uint4*)((unsigned*)y + gb + 4 * i2) = pk;
            } else {
                *(float4*)(y + gb + 4 * i2) = v;
            }
        }
    }
}

// ========== generalized MFMA conv (conv1; unchanged from R16) ==============
template<int Cin, int CINR, int H, int W, int Cout, int MT, int NT, int PACKO>
__global__ void __launch_bounds__(256) conv4s2_mfma_g(
    const unsigned* __restrict__ xp, const unsigned* __restrict__ wp,
    const float* __restrict__ bias, float* __restrict__ y)
{
    constexpr int OH = H / 2, OW = W / 2;
    constexpr int OWB = (OW >= 64) ? 64 : OW;
    constexpr int LOG_OWB = (OWB == 64) ? 6 : (OWB == 32) ? 5 : 4;
    constexpr int LOG_OW  = (OW == 128) ? 7 : (OW == 64) ? 6 : (OW == 32) ? 5 : 4;
    constexpr int R   = 64 / OWB;
    constexpr int RT  = 2 * R + 2;
    constexpr int CS  = 2 * OWB + 2;
    constexpr int XEL = 2 * RT * CS;
    constexpr int XIT = (XEL + 255) / 256;
    constexpr int K   = Cin * 16;
    constexpr int NC  = Cin / 2;
    constexpr int NB  = Cout;
    constexpr int WIT = NB / 8;
    constexpr int WN  = Cout / (16 * NT);
    constexpr int WM  = 4 / WN;
    static_assert(WM * MT * 16 == 64, "M tiling");
    static_assert(WN * NT * 16 == Cout, "N tiling");
    constexpr int MBC = 32 * OH * OW / 64;
    constexpr int XPAD = (XEL + 7) & ~7;
    constexpr int SM1 = XPAD + NB * 36;
    constexpr int SM2 = NB * 68;
    constexpr int SMEM = SM1 > SM2 ? SM1 : SM2;

    __shared__ unsigned smem[SMEM];
    unsigned* raw = smem;
    unsigned* wb  = smem + XPAD;

    int bid = blockIdx.x;
    int mb = bid % MBC, ng = bid / MBC;
    int oc0 = ng * NB;
    int m0 = mb * 64;
    int nimg = m0 / (OH * OW);
    int sp0 = m0 % (OH * OW);
    int oyb = sp0 >> LOG_OW;
    int oxb = sp0 & (OW - 1);

    int tid  = threadIdx.x;
    int lane = tid & 63, wv = tid >> 6;
    int lm = lane & 15, q = lane >> 4;
    int wm = wv / WN, wn = wv % WN;

    const unsigned* xbase = xp + (size_t)nimg * CINR * H * W;

    int  goff[XIT];
    bool gok[XIT];
    int  cidx[XIT];
#pragma unroll
    for (int s = 0; s < XIT; ++s) {
        int i = tid + 256 * s;
        goff[s] = 0; gok[s] = false; cidx[s] = 0;
        if (i < XEL) {
            int lc = i % CS;
            int t2 = i / CS;
            int lr = t2 % RT;
            int c  = t2 / RT;
            int gr = 2 * oyb - 1 + lr;
            int gc = 2 * oxb - 1 + lc;
            bool ok = ((unsigned)gr < (unsigned)H) && ((unsigned)gc < (unsigned)W);
            goff[s] = ok ? (c * H * W + gr * W + gc) : 0;
            gok[s]  = ok;
            cidx[s] = c;
        }
    }
    const unsigned* wbase = wp + (size_t)(oc0 + (tid >> 5)) * K + (tid & 31);
    int wlds0 = (tid >> 5) * 36 + (tid & 31);

    f32x4 acc[MT][NT];
#pragma unroll
    for (int nt = 0; nt < NT; ++nt) {
        float b = bias[oc0 + wn * NT * 16 + nt * 16 + lm];
#pragma unroll
        for (int mt = 0; mt < MT; ++mt)
#pragma unroll
            for (int r = 0; r < 4; ++r) acc[mt][nt][r] = b;
    }

    unsigned pfa[XIT];
    unsigned pfb[WIT];

    auto load_chunk = [&](int ch) {
        const unsigned* cb = xbase + (size_t)(ch * 2) * (H * W);
#pragma unroll
        for (int s = 0; s < XIT; ++s) {
            unsigned v = 0;
            bool okc = (2 * ch + cidx[s]) < CINR;
            if (gok[s] && okc) v = cb[goff[s]];
            pfa[s] = v;
        }
        const unsigned* wc = wbase + ch * 32;
#pragma unroll
        for (int s = 0; s < WIT; ++s) pfb[s] = wc[(size_t)s * 8 * K];
    };
    auto store_chunk = [&]() {
#pragma unroll
        for (int s = 0; s < XIT; ++s) {
            int i = tid + 256 * s;
            if (i < XEL) raw[i] = pfa[s];
        }
#pragma unroll
        for (int s = 0; s < WIT; ++s) wb[wlds0 + s * 288] = pfb[s];
    };

    load_chunk(0);
#pragma unroll 1
    for (int ch = 0; ch < NC; ++ch) {
        __syncthreads();
        store_chunk();
        __syncthreads();
        if (ch + 1 < NC) load_chunk(ch + 1);

        FragU bhi[NT], blo[NT];
#pragma unroll
        for (int nt = 0; nt < NT; ++nt) {
            const unsigned* bp = &wb[(wn * NT * 16 + nt * 16 + lm) * 36 + q * 8];
            uint4 p0 = *(const uint4*)bp;
            uint4 p1 = *(const uint4*)(bp + 4);
            unsigned e0 = p0.x, e1 = p0.y, e2 = p0.z, e3 = p0.w;
            unsigned e4 = p1.x, e5 = p1.y, e6 = p1.z, e7 = p1.w;
            bhi[nt].u[0] = (e0 & 0xffffu) | (e1 << 16);
            bhi[nt].u[1] = (e2 & 0xffffu) | (e3 << 16);
            bhi[nt].u[2] = (e4 & 0xffffu) | (e5 << 16);
            bhi[nt].u[3] = (e6 & 0xffffu) | (e7 << 16);
            blo[nt].u[0] = (e0 >> 16) | (e1 & 0xffff0000u);
            blo[nt].u[1] = (e2 >> 16) | (e3 & 0xffff0000u);
            blo[nt].u[2] = (e4 >> 16) | (e5 & 0xffff0000u);
            blo[nt].u[3] = (e6 >> 16) | (e7 & 0xffff0000u);
        }
#pragma unroll
        for (int mt = 0; mt < MT; ++mt) {
            int m = wm * (MT * 16) + mt * 16 + lm;
            int oyl = m >> LOG_OWB, oxl = m & (OWB - 1);
            int c = q >> 1, rb = 2 * oyl + (q & 1) * 2;
            const unsigned* rp = &raw[(c * RT + rb) * CS + 2 * oxl];
            uint2 a0 = *(const uint2*)rp;
            uint2 a1 = *(const uint2*)(rp + 2);
            uint2 a2 = *(const uint2*)(rp + CS);
            uint2 a3 = *(const uint2*)(rp + CS + 2);
            FragU ahi, alo;
            ahi.u[0] = (a0.x & 0xffffu) | (a0.y << 16);
            ahi.u[1] = (a1.x & 0xffffu) | (a1.y << 16);
            ahi.u[2] = (a2.x & 0xffffu) | (a2.y << 16);
            ahi.u[3] = (a3.x & 0xffffu) | (a3.y << 16);
            alo.u[0] = (a0.x >> 16) | (a0.y & 0xffff0000u);
            alo.u[1] = (a1.x >> 16) | (a1.y & 0xffff0000u);
            alo.u[2] = (a2.x >> 16) | (a2.y & 0xffff0000u);
            alo.u[3] = (a3.x >> 16) | (a3.y & 0xffff0000u);
#pragma unroll
            for (int nt = 0; nt < NT; ++nt) {
                acc[mt][nt] = __builtin_amdgcn_mfma_f32_16x16x32_bf16(
                    ahi.v, bhi[nt].v, acc[mt][nt], 0, 0, 0);
                acc[mt][nt] = __builtin_amdgcn_mfma_f32_16x16x32_bf16(
                    ahi.v, blo[nt].v, acc[mt][nt], 0, 0, 0);
                acc[mt][nt] = __builtin_amdgcn_mfma_f32_16x16x32_bf16(
                    alo.v, bhi[nt].v, acc[mt][nt], 0, 0, 0);
            }
        }
    }

    __syncthreads();
    float* cs = (float*)smem;
#pragma unroll
    for (int mt = 0; mt < MT; ++mt)
#pragma unroll
        for (int nt = 0; nt < NT; ++nt) {
            int nl  = wn * NT * 16 + nt * 16 + lm;
            int mb2 = wm * (MT * 16) + mt * 16 + q * 4;
#pragma unroll
            for (int r = 0; r < 4; ++r)
                cs[nl * 68 + mb2 + r] = acc[mt][nt][r];
        }
    __syncthreads();
    {
        constexpr int QT = 256 / NB;
        constexpr int MQ = 64 / QT;
        int nl = tid / QT, qt = tid % QT;
        size_t gb = ((size_t)(nimg * Cout + oc0 + nl)) * (OH * OW) + sp0 + qt * MQ;
#pragma unroll
        for (int i2 = 0; i2 < MQ / 4; ++i2) {
            float4 v = *(float4*)&cs[nl * 68 + qt * MQ + 4 * i2];
            v.x = fmaxf(v.x, 0.0f); v.y = fmaxf(v.y, 0.0f);
            v.z = fmaxf(v.z, 0.0f); v.w = fmaxf(v.w, 0.0f);
            if (PACKO) {
                uint4 p;
                p.x = pack_split(v.x); p.y = pack_split(v.y);
                p.z = pack_split(v.z); p.w = pack_split(v.w);
                *(uint4*)((unsigned*)y + gb + 4 * i2) = p;
            } else {
                *(float4*)(y + gb + 4 * i2) = v;
            }
        }
    }
}

// ============ MFMA ConvTranspose (parity GEMM; unchanged from R16) =========
template<int Cin, int Hh, int Wh, int Cout, int MT, int NT, int PACKO>
__global__ void __launch_bounds__(256) convt4s2_mfma(
    const unsigned* __restrict__ xp, const unsigned* __restrict__ wq,
    const float* __restrict__ bias, float* __restrict__ y)
{
    constexpr int W = Wh;
    constexpr int LOG_W = (W == 64) ? 6 : (W == 32) ? 5 : 4;
    constexpr int R   = 64 / W;
    constexpr int RT  = R + 1;
    constexpr int CS  = W + 2;
    constexpr int XEL = 8 * RT * CS;
    constexpr int XIT = (XEL + 255) / 256;
    constexpr int K   = Cin * 4;
    constexpr int K2  = K / 2;
    constexpr int NC  = Cin / 8;
    constexpr int NB  = Cout;
    constexpr int WR  = NB / 16;
    constexpr int WIT = NB / 8;
    constexpr int WN  = Cout / (16 * NT);
    constexpr int WM  = 4 / WN;
    static_assert(WM * MT * 16 == 64, "M tiling");
    static_assert(WN * NT * 16 == Cout, "N tiling");
    constexpr int MBC = 32 * Hh * W / 64;
    constexpr int XPAD = (XEL + 7) & ~7;
    constexpr int OFF_WH = XPAD;
    constexpr int OFF_WL = OFF_WH + NB * 20;
    constexpr int OFF_AH = OFF_WL + NB * 20;
    constexpr int OFF_AL = OFF_AH + 64 * 20;
    constexpr int SM1 = OFF_AL + 64 * 20;
    constexpr int SM2 = NB * 68;
    constexpr int SMEM = SM1 > SM2 ? SM1 : SM2;

    __shared__ unsigned smem[SMEM];
    unsigned* raw = smem;
    unsigned* wbh = smem + OFF_WH;
    unsigned* wbl = smem + OFF_WL;
    unsigned* afh = smem + OFF_AH;
    unsigned* afl = smem + OFF_AL;

    int bid = blockIdx.x;
    int mb  = bid % MBC;
    int par = bid / MBC;
    int dy = par >> 1, dx = par & 1;

    int m0   = mb * 64;
    int nimg = m0 / (Hh * W);
    int sp0  = m0 % (Hh * W);
    int il0  = sp0 >> LOG_W;

    int tid = threadIdx.x;
    int lane = tid & 63, wv = tid >> 6;
    int lm = lane & 15, q = lane >> 4;
    int wm = wv / WN, wn = wv % WN;

    const unsigned* xbase = xp + (size_t)nimg * Cin * Hh * W;

    int  goff[XIT];
    bool gok[XIT];
#pragma unroll
    for (int s = 0; s < XIT; ++s) {
        int i = tid + 256 * s;
        goff[s] = 0; gok[s] = false;
        if (i < XEL) {
            int lc = i % CS;
            int t2 = i / CS;
            int lr = t2 % RT;
            int c  = t2 / RT;
            int gr = il0 - 1 + dy + lr;
            int gc = lc - 1;
            bool ok = ((unsigned)gr < (unsigned)Hh) && ((unsigned)gc < (unsigned)W);
            goff[s] = ok ? (c * Hh * W + gr * W + gc) : 0;
            gok[s]  = ok;
        }
    }
    // B loader: plane stride = 4*Cout*K2 (planes outermost)
    const unsigned* wbase_h = wq + (size_t)(par * Cout + (tid >> 4)) * K2 + (tid & 15);
    const unsigned* wbase_l = wbase_h + (size_t)4 * Cout * K2;
    int wlds0 = (tid >> 4) * 20 + (tid & 15);

    f32x4 acc[MT][NT];
#pragma unroll
    for (int nt = 0; nt < NT; ++nt) {
        float b = bias[wn * NT * 16 + nt * 16 + lm];
#pragma unroll
        for (int mt = 0; mt < MT; ++mt)
#pragma unroll
            for (int r = 0; r < 4; ++r) acc[mt][nt][r] = b;
    }

    unsigned pfa[XIT];
    unsigned pfb[WIT];

    auto load_chunk = [&](int ch) {
        const unsigned* cb = xbase + (size_t)(ch * 8) * (Hh * W);
#pragma unroll
        for (int s = 0; s < XIT; ++s) {
            unsigned v = 0;
            if (gok[s]) v = cb[goff[s]];
            pfa[s] = v;
        }
        const unsigned* wch = wbase_h + ch * 16;
        const unsigned* wcl = wbase_l + ch * 16;
#pragma unroll
        for (int s = 0; s < WR; ++s) {
            pfb[2 * s]     = wch[(size_t)s * 16 * K2];
            pfb[2 * s + 1] = wcl[(size_t)s * 16 * K2];
        }
    };
    auto store_chunk = [&]() {
#pragma unroll
        for (int s = 0; s < XIT; ++s) {
            int i = tid + 256 * s;
            if (i < XEL) raw[i] = pfa[s];
        }
#pragma unroll
        for (int s = 0; s < WR; ++s) {
            wbh[wlds0 + s * 16 * 20] = pfb[2 * s];
            wbl[wlds0 + s * 16 * 20] = pfb[2 * s + 1];
        }
    };

    load_chunk(0);
#pragma unroll 1
    for (int ch = 0; ch < NC; ++ch) {
        __syncthreads();
        store_chunk();
        __syncthreads();
        {
            int m = tid >> 2, blk = tid & 3;
            int il = m >> LOG_W, jl = m & (W - 1);
            unsigned h[4], l[4];
#pragma unroll
            for (int j = 0; j < 4; ++j) {
                int kp = blk * 4 + j;
                int cl = kp >> 1, r = kp & 1;
                int ro = (cl * RT + il + r) * CS + jl + dx;
                unsigned r0 = raw[ro], r1 = raw[ro + 1];
                h[j] = (r0 & 0xffffu) | (r1 << 16);
                l[j] = (r0 >> 16) | (r1 & 0xffff0000u);
            }
            uint4 vh; vh.x = h[0]; vh.y = h[1]; vh.z = h[2]; vh.w = h[3];
            uint4 vl; vl.x = l[0]; vl.y = l[1]; vl.z = l[2]; vl.w = l[3];
            *(uint4*)&afh[m * 20 + blk * 4] = vh;
            *(uint4*)&afl[m * 20 + blk * 4] = vl;
        }
        if (ch + 1 < NC) load_chunk(ch + 1);
        __syncthreads();

        FragU bhi[NT], blo[NT];
#pragma unroll
        for (int nt = 0; nt < NT; ++nt) {
            int oc = wn * NT * 16 + nt * 16 + lm;
            uint4 th = *(const uint4*)&wbh[oc * 20 + q * 4];
            uint4 tl = *(const uint4*)&wbl[oc * 20 + q * 4];
            bhi[nt].u[0] = th.x; bhi[nt].u[1] = th.y;
            bhi[nt].u[2] = th.z; bhi[nt].u[3] = th.w;
            blo[nt].u[0] = tl.x; blo[nt].u[1] = tl.y;
            blo[nt].u[2] = tl.z; blo[nt].u[3] = tl.w;
        }
#pragma unroll
        for (int mt = 0; mt < MT; ++mt) {
            int ml = wm * (MT * 16) + mt * 16 + lm;
            uint4 ah = *(const uint4*)&afh[ml * 20 + q * 4];
            uint4 al = *(const uint4*)&afl[ml * 20 + q * 4];
            FragU ahi, alo;
            ahi.u[0] = ah.x; ahi.u[1] = ah.y; ahi.u[2] = ah.z; ahi.u[3] = ah.w;
            alo.u[0] = al.x; alo.u[1] = al.y; alo.u[2] = al.z; alo.u[3] = al.w;
#pragma unroll
            for (int nt = 0; nt < NT; ++nt) {
                acc[mt][nt] = __builtin_amdgcn_mfma_f32_16x16x32_bf16(
                    ahi.v, bhi[nt].v, acc[mt][nt], 0, 0, 0);
                acc[mt][nt] = __builtin_amdgcn_mfma_f32_16x16x32_bf16(
                    ahi.v, blo[nt].v, acc[mt][nt], 0, 0, 0);
                acc[mt][nt] = __builtin_amdgcn_mfma_f32_16x16x32_bf16(
                    alo.v, bhi[nt].v, acc[mt][nt], 0, 0, 0);
            }
        }
    }

    __syncthreads();
    float* cs = (float*)smem;
#pragma unroll
    for (int mt = 0; mt < MT; ++mt)
#pragma unroll
        for (int nt = 0; nt < NT; ++nt) {
            int nl  = wn * NT * 16 + nt * 16 + lm;
            int mb2 = wm * (MT * 16) + mt * 16 + q * 4;
#pragma unroll
            for (int r = 0; r < 4; ++r)
                cs[nl * 68 + mb2 + r] = acc[mt][nt][r];
        }
    __syncthreads();
    constexpr int EIT = NB * 64 / 256;
#pragma unroll
    for (int it = 0; it < EIT; ++it) {
        int idx = tid + 256 * it;
        int c = idx >> 6, m = idx & 63;
        int il = m >> LOG_W, jl = m & (W - 1);
        int oy = 2 * (il0 + il) + dy;
        int ox = 2 * jl + dx;
        float v = fmaxf(cs[c * 68 + m], 0.0f);
        size_t go = (((size_t)(nimg * Cout + c)) * (2 * Hh) + oy) * (2 * W) + ox;
        if (PACKO) ((unsigned*)y)[go] = pack_split(v);
        else       y[go] = v;
    }
}

// ================= direct convT (g4, tanh; unchanged) ======================
template<int Cin, int H, int W, int Cout, int COT, int ACT, int UNR>
__global__ void __launch_bounds__(256) convt4s2_k(
    const float* __restrict__ x, const float* __restrict__ w,
    const float* __restrict__ bias, float* __restrict__ y)
{
    constexpr int OH = 2 * H, OW = 2 * W, OWq = OW / 4;
    int id = blockIdx.x * 256 + threadIdx.x;
    int ox4 = id % OWq; int t = id / OWq;
    int oy  = t % OH;   t /= OH;
    int cog = t % (Cout / COT);
    int n   = t / (Cout / COT);
    int co0 = __builtin_amdgcn_readfirstlane(cog * COT);
    n       = __builtin_amdgcn_readfirstlane(n);

    int p   = (oy + 1) & 1;
    int iyA = (oy + 1 - p) >> 1;
    int iyB = iyA - 1;
    bool vA = (iyA < H);
    bool vB = (iyB >= 0);
    int iyAc = vA ? iyA : 0, iyBc = vB ? iyB : 0;

    int t0 = 2 * ox4;
    bool c0 = (t0 - 1 >= 0);
    bool c3 = (t0 + 2 <= W - 1);
    int j0 = c0 ? t0 - 1 : 0;
    int j3 = c3 ? t0 + 2 : 0;

    float acc[COT][4];
#pragma unroll
    for (int o = 0; o < COT; ++o) {
        float b = bias[co0 + o];
#pragma unroll
        for (int j = 0; j < 4; ++j) acc[o][j] = b;
    }

    const float* xn = x + (size_t)n * Cin * H * W;

#pragma unroll UNR
    for (int ci = 0; ci < Cin; ++ci) {
        const float* xc  = xn + (size_t)ci * (H * W);
        const float* xrA = xc + (size_t)iyAc * W;
        const float* xrB = xc + (size_t)iyBc * W;
        float a0 = (vA && c0) ? xrA[j0]     : 0.0f;
        float a1 =  vA        ? xrA[t0]     : 0.0f;
        float a2 =  vA        ? xrA[t0 + 1] : 0.0f;
        float a3 = (vA && c3) ? xrA[j3]     : 0.0f;
        float b0 = (vB && c0) ? xrB[j0]     : 0.0f;
        float b1 =  vB        ? xrB[t0]     : 0.0f;
        float b2 =  vB        ? xrB[t0 + 1] : 0.0f;
        float b3 = (vB && c3) ? xrB[j3]     : 0.0f;

        const float* wci = w + ((size_t)ci * Cout + co0) * 16;
#pragma unroll
        for (int o = 0; o < COT; ++o) {
            const float* wr = wci + (size_t)o * 16;
            float wA0 = wr[p * 4 + 0], wA1 = wr[p * 4 + 1];
            float wA2 = wr[p * 4 + 2], wA3 = wr[p * 4 + 3];
            float wB0 = wr[(p + 2) * 4 + 0], wB1 = wr[(p + 2) * 4 + 1];
            float wB2 = wr[(p + 2) * 4 + 2], wB3 = wr[(p + 2) * 4 + 3];
            acc[o][0] = fmaf(a1, wA1, acc[o][0]); acc[o][0] = fmaf(a0, wA3, acc[o][0]);
            acc[o][0] = fmaf(b1, wB1, acc[o][0]); acc[o][0] = fmaf(b0, wB3, acc[o][0]);
            acc[o][1] = fmaf(a2, wA0, acc[o][1]); acc[o][1] = fmaf(a1, wA2, acc[o][1]);
            acc[o][1] = fmaf(b2, wB0, acc[o][1]); acc[o][1] = fmaf(b1, wB2, acc[o][1]);
            acc[o][2] = fmaf(a2, wA1, acc[o][2]); acc[o][2] = fmaf(a1, wA3, acc[o][2]);
            acc[o][2] = fmaf(b2, wB1, acc[o][2]); acc[o][2] = fmaf(b1, wB3, acc[o][2]);
            acc[o][3] = fmaf(a3, wA0, acc[o][3]); acc[o][3] = fmaf(a2, wA2, acc[o][3]);
            acc[o][3] = fmaf(b3, wB0, acc[o][3]); acc[o][3] = fmaf(b2, wB2, acc[o][3]);
        }
    }

    int ox0 = ox4 * 4;
#pragma unroll
    for (int o = 0; o < COT; ++o) {
        float* yr = y + (((size_t)n * Cout + co0 + o) * OH + oy) * OW + ox0;
#pragma unroll
        for (int j = 0; j < 4; ++j) {
            float v = acc[o][j];
            yr[j] = (ACT == 0) ? fmaxf(v, 0.0f) : tanhf(v);
        }
    }
}

// =============================== quantizer =================================
__global__ void __launch_bounds__(256) embed_norms(
    const float* __restrict__ embed, float* __restrict__ norms)
{
    int c = blockIdx.x * 256 + threadIdx.x;
    const float* e = embed + (size_t)c * 512;
    float s = 0.0f;
    for (int k = 0; k < 512; ++k) s = fmaf(e[k], e[k], s);
    norms[c] = s;
}

__global__ void __launch_bounds__(256, 4) vq_argmin8v(
    const float* __restrict__ z, const float* __restrict__ et,
    const float* __restrict__ norms, int* __restrict__ out)
{
    constexpr int ZS = 516;
    int row0 = blockIdx.x * 8;
    int n    = row0 >> 8;
    int yx0  = row0 & 255;
    int tid  = threadIdx.x;

    __shared__ float zr[8 * ZS];

    const float* zn = z + ((size_t)n * 512) * 256;
#pragma unroll
    for (int it = 0; it < 4; ++it) {
        int i  = tid + 256 * it;
        int rq = i & 1, kc = i >> 1;
        float4 v = *(const float4*)&zn[(size_t)kc * 256 + yx0 + 4 * rq];
        zr[(4 * rq + 0) * ZS + kc] = v.x;
        zr[(4 * rq + 1) * ZS + kc] = v.y;
        zr[(4 * rq + 2) * ZS + kc] = v.z;
        zr[(4 * rq + 3) * ZS + kc] = v.w;
    }
    __syncthreads();

    f32x4 acc[8];
#pragma unroll
    for (int r = 0; r < 8; ++r) acc[r] = (f32x4){0.f, 0.f, 0.f, 0.f};

    const float* ebase = et + 4 * tid;
    f32x4 ev[4], fv[4];
#pragma unroll
    for (int j = 0; j < 4; ++j)
        ev[j] = *(const f32x4*)&ebase[(size_t)j * 1024];

#pragma unroll 1
    for (int k4 = 0; k4 < 128; ++k4) {
        int kn = (k4 + 1 < 128) ? k4 + 1 : 127;
#pragma unroll
        for (int j = 0; j < 4; ++j)
            fv[j] = *(const f32x4*)&ebase[(size_t)(4 * kn + j) * 1024];
#pragma unroll
        for (int r = 0; r < 8; ++r) {
            float4 zz = *(const float4*)&zr[r * ZS + 4 * k4];
            f32x4 a = acc[r];
            a += ev[0] * zz.x;
            a += ev[1] * zz.y;
            a += ev[2] * zz.z;
            a += ev[3] * zz.w;
            acc[r] = a;
        }
#pragma unroll
        for (int j = 0; j < 4; ++j) ev[j] = fv[j];
    }

    float4 nb = *(const float4*)&norms[4 * tid];
    float best[8]; int bi[8];
#pragma unroll
    for (int r = 0; r < 8; ++r) {
        float d0 = nb.x - 2.0f * acc[r][0];
        float d1 = nb.y - 2.0f * acc[r][1];
        float d2 = nb.z - 2.0f * acc[r][2];
        float d3 = nb.w - 2.0f * acc[r][3];
        float b = d0; int ix = 4 * tid;
        if (d1 < b) { b = d1; ix = 4 * tid + 1; }
        if (d2 < b) { b = d2; ix = 4 * tid + 2; }
        if (d3 < b) { b = d3; ix = 4 * tid + 3; }
        best[r] = b; bi[r] = ix;
    }

    __syncthreads();
    float* rbd = zr;
    int*   rbi = (int*)(zr + 2048);
#pragma unroll
    for (int r = 0; r < 8; ++r) {
        rbd[r * 256 + tid] = best[r];
        rbi[r * 256 + tid] = bi[r];
    }
    __syncthreads();
    for (int s = 128; s > 0; s >>= 1) {
        if (tid < s) {
#pragma unroll
            for (int r = 0; r < 8; ++r) {
                int i0 = r * 256 + tid;
                float od = rbd[i0 + s]; int oi = rbi[i0 + s];
                float md = rbd[i0];     int mi = rbi[i0];
                if (od < md || (od == md && oi < mi)) { rbd[i0] = od; rbi[i0] = oi; }
            }
        }
        __syncthreads();
    }
    if (tid < 8) out[row0 + tid] = rbi[tid * 256];
}

__global__ void __launch_bounds__(256) vq_gather_pack(
    const int* __restrict__ vidx, const float* __restrict__ embed,
    unsigned* __restrict__ zq)
{
    int i = blockIdx.x * 256 + threadIdx.x;
    int yx = i & 255;
    int t  = i >> 8;
    int c  = t & 511;
    int n  = t >> 9;
    int row = (n << 8) + yx;
    zq[i] = pack_split(embed[(size_t)vidx[row] * 512 + c]);
}

// ================================ launch ===================================
extern "C" void kernel_launch(void* const* d_in, const int* in_sizes, int n_in,
                              void* d_out, int out_size, void* d_ws, size_t ws_size,
                              hipStream_t stream)
{
    (void)in_sizes; (void)n_in; (void)out_size; (void)ws_size;
    const float* x     = (const float*)d_in[0];
    const float* ew1   = (const float*)d_in[1];
    const float* eb1   = (const float*)d_in[2];
    const float* ew2   = (const float*)d_in[3];
    const float* eb2   = (const float*)d_in[4];
    const float* ew3   = (const float*)d_in[5];
    const float* eb3   = (const float*)d_in[6];
    const float* ew4   = (const float*)d_in[7];
    const float* eb4   = (const float*)d_in[8];
    const float* dw1   = (const float*)d_in[9];
    const float* db1   = (const float*)d_in[10];
    const float* dw2   = (const float*)d_in[11];
    const float* db2   = (const float*)d_in[12];
    const float* dw3   = (const float*)d_in[13];
    const float* db3   = (const float*)d_in[14];
    const float* dw4   = (const float*)d_in[15];
    const float* db4   = (const float*)d_in[16];
    const float* embed = (const float*)d_in[17];
    float* out = (float*)d_out;

    // ---- workspace layout (u32 units). Identical to R16.
    unsigned* W0   = (unsigned*)d_ws;
    unsigned* h1p  = W0;
    unsigned* h2p  = W0 + 33554432;
    unsigned* xp1  = W0 + 33554432;
    unsigned* h3p  = W0;
    float*    z    = (float*)(W0 + 8388608);
    unsigned* zq   = W0 + 12582912;
    float*    P0   = (float*)(W0 + 16777216);
    float*    P1   = (float*)(W0 + 20971520);
    int*      vidx = (int*)(W0 + 29360128);
    float*    norms= (float*)(W0 + 29368320);
    float*    g3o  = (float*)h2p;

    // packed weights + transposed codebook live in d_out until g4 overwrites
    unsigned* wp2 = (unsigned*)d_out;             // 131,072  (2 planes)
    unsigned* wp3 = wp2 + 131072;                 // 524,288
    unsigned* wp4 = wp2 + 655360;                 // 2,097,152
    unsigned* wq1 = wp2 + 2752512;                // 1,048,576
    unsigned* wq2 = wq1 + 1048576;                // 131,072
    unsigned* wq3 = wq2 + 131072;                 // 32,768
    float*    et  = (float*)(wq3 + 32768);        // 524,288 (512x1024)
    unsigned* wp1 = (unsigned*)(et + 524288);     // 4,096 (64x64 padded)

    dim3 b256(256);

    // ---- pre-pass: pair-plane weight packs, input pack, codebook ----
    pack_w_planes<128, 1024><<<dim3(512),  b256, 0, stream>>>(ew2, wp2);
    pack_w_planes<256, 2048><<<dim3(2048), b256, 0, stream>>>(ew3, wp3);
    pack_w_planes<512, 4096><<<dim3(8192), b256, 0, stream>>>(ew4, wp4);
    pack_w1<<<dim3(16), b256, 0, stream>>>(ew1, wp1);
    pack_tensor<<<dim3(24576), b256, 0, stream>>>(x, xp1, 6291456);
    repack_wt_planes<512, 128><<<dim3(4096), b256, 0, stream>>>(dw1, wq1);
    repack_wt_planes<128,  64><<<dim3(512),  b256, 0, stream>>>(dw2, wq2);
    repack_wt_planes< 64,  32><<<dim3(128),  b256, 0, stream>>>(dw3, wq3);
    embed_transpose<<<dim3(2048), b256, 0, stream>>>(embed, et);

    // ---- encoder ----
    conv4s2_mfma_g<4, 3, 256, 256, 64, 4, 1, 1><<<dim3(8192), b256, 0, stream>>>(
        xp1, wp1, eb1, (float*)h1p);                       // h1 (packed)
    conv4s2_mfma<64, 128, 128, 128, 128, 1><<<dim3(2048), b256, 0, stream>>>(
        h1p, wp2, eb2, (float*)h2p);                       // h2 (packed)
    conv4s2_mfma<128, 64, 64, 256, 128, 1><<<dim3(1024), b256, 0, stream>>>(
        h2p, wp3, eb3, (float*)h3p);                       // h3 (packed)
    conv4s2_mfma<256, 32, 32, 512, 64, 0><<<dim3(1024), b256, 0, stream>>>(
        h3p, wp4, eb4, z);                                 // z (fp32)

    // ---- quantizer ----
    embed_norms<<<dim3(4), b256, 0, stream>>>(embed, norms);
    vq_argmin8v<<<dim3(1024), b256, 0, stream>>>(z, et, norms, vidx);
    vq_gather_pack<<<dim3(16384), b256, 0, stream>>>(vidx, embed, zq);

    // ---- decoder (MFMA parity-GEMM convT) ----
    convt4s2_mfma<512, 16, 16, 128, 4, 2, 1><<<dim3(4 * 128), b256, 0, stream>>>(
        zq, wq1, db1, P0);                                 // P0 (packed)
    convt4s2_mfma<128, 32, 32, 64, 4, 1, 1><<<dim3(4 * 512), b256, 0, stream>>>(
        (const unsigned*)P0, wq2, db2, P1);                // P1 (packed)
    convt4s2_mfma<64, 64, 64, 32, 2, 1, 0><<<dim3(4 * 2048), b256, 0, stream>>>(
        (const unsigned*)P1, wq3, db3, g3o);               // g3o (fp32)
    convt4s2_k<32, 128, 128, 3, 3, 1, 2><<<dim3(2048), b256, 0, stream>>>(
        g3o, dw4, db4, out);                               // tanh -> d_out
}

// Round 11
// 1108.872 us; speedup vs baseline: 1.0870x; 1.0870x over previous
//
#include <hip/hip_runtime.h>
#include <math.h>

// ---------------------------------------------------------------------------
// VQ-VAE forward. Round 18: consolidation of best-measured variants.
// R13-R17 record: conv template's pair-plane B path (R15+) carries a fixed
// 46M-conflict term (conv2 216-228us) vs R13's VALU-repack form (199us,
// 4.2M conflicts); convT's pair-plane port (R15/16) is a win. So:
//  - conv4s2_mfma: reverted to R13 exactly (plain packed weights, NB param).
//  - convt4s2_mfma: R16 pair-plane version.
//  - conv1 / quantizer / g4: R16 (proven).
// ---------------------------------------------------------------------------

typedef __attribute__((ext_vector_type(8))) short bf16x8;
typedef __attribute__((ext_vector_type(4))) float f32x4;
union FragU { unsigned u[4]; bf16x8 v; };

__device__ __forceinline__ unsigned bf16_rne(unsigned u) {
    return (u + 0x7FFFu + ((u >> 16) & 1u)) >> 16;
}
// pack fp32 -> u32: low16 = bf16(v), high16 = bf16(v - bf16(v))
__device__ __forceinline__ unsigned pack_split(float v) {
    unsigned u = __builtin_bit_cast(unsigned, v);
    unsigned hi = bf16_rne(u);
    float hif = __builtin_bit_cast(float, hi << 16);
    float r = v - hif;
    unsigned lo = bf16_rne(__builtin_bit_cast(unsigned, r));
    return hi | (lo << 16);
}

__global__ void __launch_bounds__(256) pack_tensor(
    const float* __restrict__ s, unsigned* __restrict__ d, int n)
{
    int i = blockIdx.x * 256 + threadIdx.x;
    if (i < n) d[i] = pack_split(s[i]);
}

// conv1 weights (64,3,4,4) -> padded packed [64][64] (k>=48 zero)
__global__ void __launch_bounds__(256) pack_w1(
    const float* __restrict__ w, unsigned* __restrict__ wq)
{
    int idx = blockIdx.x * 256 + threadIdx.x;
    if (idx >= 64 * 64) return;
    int k = idx & 63, oc = idx >> 6;
    float v = (k < 48) ? w[oc * 48 + k] : 0.0f;
    wq[idx] = pack_split(v);
}

// ConvTranspose weights (torch Cin,Cout,4,4) -> pair-planes
// [2][par][Cout][K/2], K = Cin*4, k = ci*4 + (2r+s), par = dy*2+dx.
template<int Cin, int Cout>
__global__ void __launch_bounds__(256) repack_wt_planes(
    const float* __restrict__ w, unsigned* __restrict__ wq)
{
    constexpr int K = Cin * 4, K2 = K / 2;
    constexpr int TOT = 2 * 4 * Cout * K2;
    int idx = blockIdx.x * 256 + threadIdx.x;
    if (idx >= TOT) return;
    int kp   = idx % K2;
    int rest = idx / K2;
    int co   = rest % Cout;
    rest    /= Cout;
    int par  = rest & 3;
    int p    = rest >> 2;
    int dy = par >> 1, dx = par & 1;
    unsigned u01[2];
#pragma unroll
    for (int e = 0; e < 2; ++e) {
        int k = 2 * kp + e;
        int t = k & 3, ci = k >> 2;
        int r = t >> 1, s = t & 1;
        int ky = 3 - dy - 2 * r;
        int kx = 3 - dx - 2 * s;
        u01[e] = pack_split(w[(((size_t)ci * Cout + co) * 4 + ky) * 4 + kx]);
    }
    wq[idx] = (p == 0) ? ((u01[0] & 0xffffu) | (u01[1] << 16))
                       : ((u01[0] >> 16) | (u01[1] & 0xffff0000u));
}

// transpose codebook: embed[1024][512] -> et[512][1024]
__global__ void __launch_bounds__(256) embed_transpose(
    const float* __restrict__ embed, float* __restrict__ et)
{
    int idx = blockIdx.x * 256 + threadIdx.x;
    int c = idx & 1023, k = idx >> 10;
    et[idx] = embed[(size_t)c * 512 + k];
}

// ================= MFMA conv k=4 s=2 p=1 + ReLU (implicit GEMM) ============
// R13 version (best measured: conv2 199us). NB = oc per block (64 or 128).
template<int Cin, int H, int W, int Cout, int NB, int PACKO>
__global__ void __launch_bounds__(256) conv4s2_mfma(
    const unsigned* __restrict__ xp, const unsigned* __restrict__ wp,
    const float* __restrict__ bias, float* __restrict__ y)
{
    constexpr int OH = H / 2, OW = W / 2;
    constexpr int LOG_OW = (OW == 64) ? 6 : (OW == 32) ? 5 : 4;
    constexpr int R   = 64 / OW;
    constexpr int RT  = 2 * R + 2;
    constexpr int CS  = W + 2;
    constexpr int XEL = 2 * RT * CS;
    constexpr int XIT = (XEL + 255) / 256;
    constexpr int K   = Cin * 16;
    constexpr int NC  = Cin / 2;
    constexpr int NT  = NB / 64;            // oc 16-tiles per wave
    constexpr int WIT = NB / 8;             // B-load iterations
    constexpr int MBC = 32 * OH * OW / 64;
    constexpr int XPAD = (XEL + 7) & ~7;
    constexpr int SM1 = XPAD + NB * 36;
    constexpr int SM2 = NB * 68;
    constexpr int SMEM = SM1 > SM2 ? SM1 : SM2;

    __shared__ unsigned smem[SMEM];
    unsigned* raw = smem;
    unsigned* wb  = smem + XPAD;

    int bid = blockIdx.x;
    int mb = bid % MBC, ng = bid / MBC;
    int oc0 = ng * NB;
    int m0 = mb * 64;
    int nimg = m0 / (OH * OW);
    int sp0 = m0 % (OH * OW);
    int oyb = sp0 >> LOG_OW;

    int tid  = threadIdx.x;
    int lane = tid & 63, wv = tid >> 6;
    int lm = lane & 15, q = lane >> 4;
    int n0w = wv * 16 * NT;

    const unsigned* xbase = xp + (size_t)nimg * Cin * H * W;

    int  goff[XIT];
    bool gok[XIT];
#pragma unroll
    for (int s = 0; s < XIT; ++s) {
        int i = tid + 256 * s;
        goff[s] = 0; gok[s] = false;
        if (i < XEL) {
            int lc = i % CS;
            int t2 = i / CS;
            int lr = t2 % RT;
            int c  = t2 / RT;
            int gr = 2 * oyb - 1 + lr;
            int gc = lc - 1;
            bool ok = ((unsigned)gr < (unsigned)H) && ((unsigned)gc < (unsigned)W);
            goff[s] = ok ? (c * H * W + gr * W + gc) : 0;
            gok[s]  = ok;
        }
    }
    const unsigned* wbase = wp + (size_t)(oc0 + (tid >> 5)) * K + (tid & 31);
    int wlds0 = (tid >> 5) * 36 + (tid & 31);

    f32x4 acc[4][NT];
#pragma unroll
    for (int nt = 0; nt < NT; ++nt) {
        float b = bias[oc0 + n0w + nt * 16 + lm];
#pragma unroll
        for (int mt = 0; mt < 4; ++mt)
#pragma unroll
            for (int r = 0; r < 4; ++r) acc[mt][nt][r] = b;
    }

    unsigned pfa[XIT];
    unsigned pfb[WIT];

    auto load_chunk = [&](int ch) {
        const unsigned* cb = xbase + (size_t)(ch * 2) * (H * W);
#pragma unroll
        for (int s = 0; s < XIT; ++s) {
            unsigned v = 0;
            if (gok[s]) v = cb[goff[s]];
            pfa[s] = v;
        }
        const unsigned* wc = wbase + ch * 32;
#pragma unroll
        for (int s = 0; s < WIT; ++s) pfb[s] = wc[(size_t)s * 8 * K];
    };
    auto store_chunk = [&]() {
#pragma unroll
        for (int s = 0; s < XIT; ++s) {
            int i = tid + 256 * s;
            if (i < XEL) raw[i] = pfa[s];
        }
#pragma unroll
        for (int s = 0; s < WIT; ++s) wb[wlds0 + s * 288] = pfb[s];
    };

    load_chunk(0);
#pragma unroll 1
    for (int ch = 0; ch < NC; ++ch) {
        __syncthreads();
        store_chunk();
        __syncthreads();
        if (ch + 1 < NC) load_chunk(ch + 1);

        FragU bhi[NT], blo[NT];
#pragma unroll
        for (int nt = 0; nt < NT; ++nt) {
            const unsigned* bp = &wb[(n0w + nt * 16 + lm) * 36 + q * 8];
            uint4 p0 = *(const uint4*)bp;
            uint4 p1 = *(const uint4*)(bp + 4);
            unsigned e0 = p0.x, e1 = p0.y, e2 = p0.z, e3 = p0.w;
            unsigned e4 = p1.x, e5 = p1.y, e6 = p1.z, e7 = p1.w;
            bhi[nt].u[0] = (e0 & 0xffffu) | (e1 << 16);
            bhi[nt].u[1] = (e2 & 0xffffu) | (e3 << 16);
            bhi[nt].u[2] = (e4 & 0xffffu) | (e5 << 16);
            bhi[nt].u[3] = (e6 & 0xffffu) | (e7 << 16);
            blo[nt].u[0] = (e0 >> 16) | (e1 & 0xffff0000u);
            blo[nt].u[1] = (e2 >> 16) | (e3 & 0xffff0000u);
            blo[nt].u[2] = (e4 >> 16) | (e5 & 0xffff0000u);
            blo[nt].u[3] = (e6 >> 16) | (e7 & 0xffff0000u);
        }
#pragma unroll
        for (int mt = 0; mt < 4; ++mt) {
            int m = mt * 16 + lm;
            int oyl = m >> LOG_OW, oxl = m & (OW - 1);
            int c = q >> 1, rb = 2 * oyl + (q & 1) * 2;
            const unsigned* rp = &raw[(c * RT + rb) * CS + 2 * oxl];
            uint2 a0 = *(const uint2*)rp;
            uint2 a1 = *(const uint2*)(rp + 2);
            uint2 a2 = *(const uint2*)(rp + CS);
            uint2 a3 = *(const uint2*)(rp + CS + 2);
            FragU ahi, alo;
            ahi.u[0] = (a0.x & 0xffffu) | (a0.y << 16);
            ahi.u[1] = (a1.x & 0xffffu) | (a1.y << 16);
            ahi.u[2] = (a2.x & 0xffffu) | (a2.y << 16);
            ahi.u[3] = (a3.x & 0xffffu) | (a3.y << 16);
            alo.u[0] = (a0.x >> 16) | (a0.y & 0xffff0000u);
            alo.u[1] = (a1.x >> 16) | (a1.y & 0xffff0000u);
            alo.u[2] = (a2.x >> 16) | (a2.y & 0xffff0000u);
            alo.u[3] = (a3.x >> 16) | (a3.y & 0xffff0000u);
#pragma unroll
            for (int nt = 0; nt < NT; ++nt) {
                acc[mt][nt] = __builtin_amdgcn_mfma_f32_16x16x32_bf16(
                    ahi.v, bhi[nt].v, acc[mt][nt], 0, 0, 0);
                acc[mt][nt] = __builtin_amdgcn_mfma_f32_16x16x32_bf16(
                    ahi.v, blo[nt].v, acc[mt][nt], 0, 0, 0);
                acc[mt][nt] = __builtin_amdgcn_mfma_f32_16x16x32_bf16(
                    alo.v, bhi[nt].v, acc[mt][nt], 0, 0, 0);
            }
        }
    }

    __syncthreads();
    float* cs = (float*)smem;
#pragma unroll
    for (int mt = 0; mt < 4; ++mt)
#pragma unroll
        for (int nt = 0; nt < NT; ++nt) {
            int nl = n0w + nt * 16 + lm;
#pragma unroll
            for (int r = 0; r < 4; ++r)
                cs[nl * 68 + mt * 16 + q * 4 + r] = acc[mt][nt][r];
        }
    __syncthreads();
    {
        constexpr int QT = 256 / NB;            // threads per channel
        constexpr int MQ = 64 / QT;             // m per thread
        int nl = tid / QT, qt = tid % QT;
        size_t gb = ((size_t)(nimg * Cout + oc0 + nl)) * (OH * OW) + sp0 + qt * MQ;
#pragma unroll
        for (int i2 = 0; i2 < MQ / 4; ++i2) {
            float4 v = *(float4*)&cs[nl * 68 + qt * MQ + 4 * i2];
            v.x = fmaxf(v.x, 0.0f); v.y = fmaxf(v.y, 0.0f);
            v.z = fmaxf(v.z, 0.0f); v.w = fmaxf(v.w, 0.0f);
            if (PACKO) {
                uint4 p;
                p.x = pack_split(v.x); p.y = pack_split(v.y);
                p.z = pack_split(v.z); p.w = pack_split(v.w);
                *(uint4*)((unsigned*)y + gb + 4 * i2) = p;
            } else {
                *(float4*)(y + gb + 4 * i2) = v;
            }
        }
    }
}

// ========== generalized MFMA conv (conv1; unchanged) =======================
template<int Cin, int CINR, int H, int W, int Cout, int MT, int NT, int PACKO>
__global__ void __launch_bounds__(256) conv4s2_mfma_g(
    const unsigned* __restrict__ xp, const unsigned* __restrict__ wp,
    const float* __restrict__ bias, float* __restrict__ y)
{
    constexpr int OH = H / 2, OW = W / 2;
    constexpr int OWB = (OW >= 64) ? 64 : OW;
    constexpr int LOG_OWB = (OWB == 64) ? 6 : (OWB == 32) ? 5 : 4;
    constexpr int LOG_OW  = (OW == 128) ? 7 : (OW == 64) ? 6 : (OW == 32) ? 5 : 4;
    constexpr int R   = 64 / OWB;
    constexpr int RT  = 2 * R + 2;
    constexpr int CS  = 2 * OWB + 2;
    constexpr int XEL = 2 * RT * CS;
    constexpr int XIT = (XEL + 255) / 256;
    constexpr int K   = Cin * 16;
    constexpr int NC  = Cin / 2;
    constexpr int NB  = Cout;
    constexpr int WIT = NB / 8;
    constexpr int WN  = Cout / (16 * NT);
    constexpr int WM  = 4 / WN;
    static_assert(WM * MT * 16 == 64, "M tiling");
    static_assert(WN * NT * 16 == Cout, "N tiling");
    constexpr int MBC = 32 * OH * OW / 64;
    constexpr int XPAD = (XEL + 7) & ~7;
    constexpr int SM1 = XPAD + NB * 36;
    constexpr int SM2 = NB * 68;
    constexpr int SMEM = SM1 > SM2 ? SM1 : SM2;

    __shared__ unsigned smem[SMEM];
    unsigned* raw = smem;
    unsigned* wb  = smem + XPAD;

    int bid = blockIdx.x;
    int mb = bid % MBC, ng = bid / MBC;
    int oc0 = ng * NB;
    int m0 = mb * 64;
    int nimg = m0 / (OH * OW);
    int sp0 = m0 % (OH * OW);
    int oyb = sp0 >> LOG_OW;
    int oxb = sp0 & (OW - 1);

    int tid  = threadIdx.x;
    int lane = tid & 63, wv = tid >> 6;
    int lm = lane & 15, q = lane >> 4;
    int wm = wv / WN, wn = wv % WN;

    const unsigned* xbase = xp + (size_t)nimg * CINR * H * W;

    int  goff[XIT];
    bool gok[XIT];
    int  cidx[XIT];
#pragma unroll
    for (int s = 0; s < XIT; ++s) {
        int i = tid + 256 * s;
        goff[s] = 0; gok[s] = false; cidx[s] = 0;
        if (i < XEL) {
            int lc = i % CS;
            int t2 = i / CS;
            int lr = t2 % RT;
            int c  = t2 / RT;
            int gr = 2 * oyb - 1 + lr;
            int gc = 2 * oxb - 1 + lc;
            bool ok = ((unsigned)gr < (unsigned)H) && ((unsigned)gc < (unsigned)W);
            goff[s] = ok ? (c * H * W + gr * W + gc) : 0;
            gok[s]  = ok;
            cidx[s] = c;
        }
    }
    const unsigned* wbase = wp + (size_t)(oc0 + (tid >> 5)) * K + (tid & 31);
    int wlds0 = (tid >> 5) * 36 + (tid & 31);

    f32x4 acc[MT][NT];
#pragma unroll
    for (int nt = 0; nt < NT; ++nt) {
        float b = bias[oc0 + wn * NT * 16 + nt * 16 + lm];
#pragma unroll
        for (int mt = 0; mt < MT; ++mt)
#pragma unroll
            for (int r = 0; r < 4; ++r) acc[mt][nt][r] = b;
    }

    unsigned pfa[XIT];
    unsigned pfb[WIT];

    auto load_chunk = [&](int ch) {
        const unsigned* cb = xbase + (size_t)(ch * 2) * (H * W);
#pragma unroll
        for (int s = 0; s < XIT; ++s) {
            unsigned v = 0;
            bool okc = (2 * ch + cidx[s]) < CINR;
            if (gok[s] && okc) v = cb[goff[s]];
            pfa[s] = v;
        }
        const unsigned* wc = wbase + ch * 32;
#pragma unroll
        for (int s = 0; s < WIT; ++s) pfb[s] = wc[(size_t)s * 8 * K];
    };
    auto store_chunk = [&]() {
#pragma unroll
        for (int s = 0; s < XIT; ++s) {
            int i = tid + 256 * s;
            if (i < XEL) raw[i] = pfa[s];
        }
#pragma unroll
        for (int s = 0; s < WIT; ++s) wb[wlds0 + s * 288] = pfb[s];
    };

    load_chunk(0);
#pragma unroll 1
    for (int ch = 0; ch < NC; ++ch) {
        __syncthreads();
        store_chunk();
        __syncthreads();
        if (ch + 1 < NC) load_chunk(ch + 1);

        FragU bhi[NT], blo[NT];
#pragma unroll
        for (int nt = 0; nt < NT; ++nt) {
            const unsigned* bp = &wb[(wn * NT * 16 + nt * 16 + lm) * 36 + q * 8];
            uint4 p0 = *(const uint4*)bp;
            uint4 p1 = *(const uint4*)(bp + 4);
            unsigned e0 = p0.x, e1 = p0.y, e2 = p0.z, e3 = p0.w;
            unsigned e4 = p1.x, e5 = p1.y, e6 = p1.z, e7 = p1.w;
            bhi[nt].u[0] = (e0 & 0xffffu) | (e1 << 16);
            bhi[nt].u[1] = (e2 & 0xffffu) | (e3 << 16);
            bhi[nt].u[2] = (e4 & 0xffffu) | (e5 << 16);
            bhi[nt].u[3] = (e6 & 0xffffu) | (e7 << 16);
            blo[nt].u[0] = (e0 >> 16) | (e1 & 0xffff0000u);
            blo[nt].u[1] = (e2 >> 16) | (e3 & 0xffff0000u);
            blo[nt].u[2] = (e4 >> 16) | (e5 & 0xffff0000u);
            blo[nt].u[3] = (e6 >> 16) | (e7 & 0xffff0000u);
        }
#pragma unroll
        for (int mt = 0; mt < MT; ++mt) {
            int m = wm * (MT * 16) + mt * 16 + lm;
            int oyl = m >> LOG_OWB, oxl = m & (OWB - 1);
            int c = q >> 1, rb = 2 * oyl + (q & 1) * 2;
            const unsigned* rp = &raw[(c * RT + rb) * CS + 2 * oxl];
            uint2 a0 = *(const uint2*)rp;
            uint2 a1 = *(const uint2*)(rp + 2);
            uint2 a2 = *(const uint2*)(rp + CS);
            uint2 a3 = *(const uint2*)(rp + CS + 2);
            FragU ahi, alo;
            ahi.u[0] = (a0.x & 0xffffu) | (a0.y << 16);
            ahi.u[1] = (a1.x & 0xffffu) | (a1.y << 16);
            ahi.u[2] = (a2.x & 0xffffu) | (a2.y << 16);
            ahi.u[3] = (a3.x & 0xffffu) | (a3.y << 16);
            alo.u[0] = (a0.x >> 16) | (a0.y & 0xffff0000u);
            alo.u[1] = (a1.x >> 16) | (a1.y & 0xffff0000u);
            alo.u[2] = (a2.x >> 16) | (a2.y & 0xffff0000u);
            alo.u[3] = (a3.x >> 16) | (a3.y & 0xffff0000u);
#pragma unroll
            for (int nt = 0; nt < NT; ++nt) {
                acc[mt][nt] = __builtin_amdgcn_mfma_f32_16x16x32_bf16(
                    ahi.v, bhi[nt].v, acc[mt][nt], 0, 0, 0);
                acc[mt][nt] = __builtin_amdgcn_mfma_f32_16x16x32_bf16(
                    ahi.v, blo[nt].v, acc[mt][nt], 0, 0, 0);
                acc[mt][nt] = __builtin_amdgcn_mfma_f32_16x16x32_bf16(
                    alo.v, bhi[nt].v, acc[mt][nt], 0, 0, 0);
            }
        }
    }

    __syncthreads();
    float* cs = (float*)smem;
#pragma unroll
    for (int mt = 0; mt < MT; ++mt)
#pragma unroll
        for (int nt = 0; nt < NT; ++nt) {
            int nl  = wn * NT * 16 + nt * 16 + lm;
            int mb2 = wm * (MT * 16) + mt * 16 + q * 4;
#pragma unroll
            for (int r = 0; r < 4; ++r)
                cs[nl * 68 + mb2 + r] = acc[mt][nt][r];
        }
    __syncthreads();
    {
        constexpr int QT = 256 / NB;
        constexpr int MQ = 64 / QT;
        int nl = tid / QT, qt = tid % QT;
        size_t gb = ((size_t)(nimg * Cout + oc0 + nl)) * (OH * OW) + sp0 + qt * MQ;
#pragma unroll
        for (int i2 = 0; i2 < MQ / 4; ++i2) {
            float4 v = *(float4*)&cs[nl * 68 + qt * MQ + 4 * i2];
            v.x = fmaxf(v.x, 0.0f); v.y = fmaxf(v.y, 0.0f);
            v.z = fmaxf(v.z, 0.0f); v.w = fmaxf(v.w, 0.0f);
            if (PACKO) {
                uint4 p;
                p.x = pack_split(v.x); p.y = pack_split(v.y);
                p.z = pack_split(v.z); p.w = pack_split(v.w);
                *(uint4*)((unsigned*)y + gb + 4 * i2) = p;
            } else {
                *(float4*)(y + gb + 4 * i2) = v;
            }
        }
    }
}

// ============ MFMA ConvTranspose (parity GEMM; R16 pair-plane) =============
template<int Cin, int Hh, int Wh, int Cout, int MT, int NT, int PACKO>
__global__ void __launch_bounds__(256) convt4s2_mfma(
    const unsigned* __restrict__ xp, const unsigned* __restrict__ wq,
    const float* __restrict__ bias, float* __restrict__ y)
{
    constexpr int W = Wh;
    constexpr int LOG_W = (W == 64) ? 6 : (W == 32) ? 5 : 4;
    constexpr int R   = 64 / W;
    constexpr int RT  = R + 1;
    constexpr int CS  = W + 2;
    constexpr int XEL = 8 * RT * CS;
    constexpr int XIT = (XEL + 255) / 256;
    constexpr int K   = Cin * 4;
    constexpr int K2  = K / 2;
    constexpr int NC  = Cin / 8;
    constexpr int NB  = Cout;
    constexpr int WR  = NB / 16;
    constexpr int WIT = NB / 8;
    constexpr int WN  = Cout / (16 * NT);
    constexpr int WM  = 4 / WN;
    static_assert(WM * MT * 16 == 64, "M tiling");
    static_assert(WN * NT * 16 == Cout, "N tiling");
    constexpr int MBC = 32 * Hh * W / 64;
    constexpr int XPAD = (XEL + 7) & ~7;
    constexpr int OFF_WH = XPAD;
    constexpr int OFF_WL = OFF_WH + NB * 20;
    constexpr int OFF_AH = OFF_WL + NB * 20;
    constexpr int OFF_AL = OFF_AH + 64 * 20;
    constexpr int SM1 = OFF_AL + 64 * 20;
    constexpr int SM2 = NB * 68;
    constexpr int SMEM = SM1 > SM2 ? SM1 : SM2;

    __shared__ unsigned smem[SMEM];
    unsigned* raw = smem;
    unsigned* wbh = smem + OFF_WH;
    unsigned* wbl = smem + OFF_WL;
    unsigned* afh = smem + OFF_AH;
    unsigned* afl = smem + OFF_AL;

    int bid = blockIdx.x;
    int mb  = bid % MBC;
    int par = bid / MBC;
    int dy = par >> 1, dx = par & 1;

    int m0   = mb * 64;
    int nimg = m0 / (Hh * W);
    int sp0  = m0 % (Hh * W);
    int il0  = sp0 >> LOG_W;

    int tid = threadIdx.x;
    int lane = tid & 63, wv = tid >> 6;
    int lm = lane & 15, q = lane >> 4;
    int wm = wv / WN, wn = wv % WN;

    const unsigned* xbase = xp + (size_t)nimg * Cin * Hh * W;

    int  goff[XIT];
    bool gok[XIT];
#pragma unroll
    for (int s = 0; s < XIT; ++s) {
        int i = tid + 256 * s;
        goff[s] = 0; gok[s] = false;
        if (i < XEL) {
            int lc = i % CS;
            int t2 = i / CS;
            int lr = t2 % RT;
            int c  = t2 / RT;
            int gr = il0 - 1 + dy + lr;
            int gc = lc - 1;
            bool ok = ((unsigned)gr < (unsigned)Hh) && ((unsigned)gc < (unsigned)W);
            goff[s] = ok ? (c * Hh * W + gr * W + gc) : 0;
            gok[s]  = ok;
        }
    }
    // B loader: plane stride = 4*Cout*K2 (planes outermost)
    const unsigned* wbase_h = wq + (size_t)(par * Cout + (tid >> 4)) * K2 + (tid & 15);
    const unsigned* wbase_l = wbase_h + (size_t)4 * Cout * K2;
    int wlds0 = (tid >> 4) * 20 + (tid & 15);

    f32x4 acc[MT][NT];
#pragma unroll
    for (int nt = 0; nt < NT; ++nt) {
        float b = bias[wn * NT * 16 + nt * 16 + lm];
#pragma unroll
        for (int mt = 0; mt < MT; ++mt)
#pragma unroll
            for (int r = 0; r < 4; ++r) acc[mt][nt][r] = b;
    }

    unsigned pfa[XIT];
    unsigned pfb[WIT];

    auto load_chunk = [&](int ch) {
        const unsigned* cb = xbase + (size_t)(ch * 8) * (Hh * W);
#pragma unroll
        for (int s = 0; s < XIT; ++s) {
            unsigned v = 0;
            if (gok[s]) v = cb[goff[s]];
            pfa[s] = v;
        }
        const unsigned* wch = wbase_h + ch * 16;
        const unsigned* wcl = wbase_l + ch * 16;
#pragma unroll
        for (int s = 0; s < WR; ++s) {
            pfb[2 * s]     = wch[(size_t)s * 16 * K2];
            pfb[2 * s + 1] = wcl[(size_t)s * 16 * K2];
        }
    };
    auto store_chunk = [&]() {
#pragma unroll
        for (int s = 0; s < XIT; ++s) {
            int i = tid + 256 * s;
            if (i < XEL) raw[i] = pfa[s];
        }
#pragma unroll
        for (int s = 0; s < WR; ++s) {
            wbh[wlds0 + s * 16 * 20] = pfb[2 * s];
            wbl[wlds0 + s * 16 * 20] = pfb[2 * s + 1];
        }
    };

    load_chunk(0);
#pragma unroll 1
    for (int ch = 0; ch < NC; ++ch) {
        __syncthreads();
        store_chunk();
        __syncthreads();
        {
            int m = tid >> 2, blk = tid & 3;
            int il = m >> LOG_W, jl = m & (W - 1);
            unsigned h[4], l[4];
#pragma unroll
            for (int j = 0; j < 4; ++j) {
                int kp = blk * 4 + j;
                int cl = kp >> 1, r = kp & 1;
                int ro = (cl * RT + il + r) * CS + jl + dx;
                unsigned r0 = raw[ro], r1 = raw[ro + 1];
                h[j] = (r0 & 0xffffu) | (r1 << 16);
                l[j] = (r0 >> 16) | (r1 & 0xffff0000u);
            }
            uint4 vh; vh.x = h[0]; vh.y = h[1]; vh.z = h[2]; vh.w = h[3];
            uint4 vl; vl.x = l[0]; vl.y = l[1]; vl.z = l[2]; vl.w = l[3];
            *(uint4*)&afh[m * 20 + blk * 4] = vh;
            *(uint4*)&afl[m * 20 + blk * 4] = vl;
        }
        if (ch + 1 < NC) load_chunk(ch + 1);
        __syncthreads();

        FragU bhi[NT], blo[NT];
#pragma unroll
        for (int nt = 0; nt < NT; ++nt) {
            int oc = wn * NT * 16 + nt * 16 + lm;
            uint4 th = *(const uint4*)&wbh[oc * 20 + q * 4];
            uint4 tl = *(const uint4*)&wbl[oc * 20 + q * 4];
            bhi[nt].u[0] = th.x; bhi[nt].u[1] = th.y;
            bhi[nt].u[2] = th.z; bhi[nt].u[3] = th.w;
            blo[nt].u[0] = tl.x; blo[nt].u[1] = tl.y;
            blo[nt].u[2] = tl.z; blo[nt].u[3] = tl.w;
        }
#pragma unroll
        for (int mt = 0; mt < MT; ++mt) {
            int ml = wm * (MT * 16) + mt * 16 + lm;
            uint4 ah = *(const uint4*)&afh[ml * 20 + q * 4];
            uint4 al = *(const uint4*)&afl[ml * 20 + q * 4];
            FragU ahi, alo;
            ahi.u[0] = ah.x; ahi.u[1] = ah.y; ahi.u[2] = ah.z; ahi.u[3] = ah.w;
            alo.u[0] = al.x; alo.u[1] = al.y; alo.u[2] = al.z; alo.u[3] = al.w;
#pragma unroll
            for (int nt = 0; nt < NT; ++nt) {
                acc[mt][nt] = __builtin_amdgcn_mfma_f32_16x16x32_bf16(
                    ahi.v, bhi[nt].v, acc[mt][nt], 0, 0, 0);
                acc[mt][nt] = __builtin_amdgcn_mfma_f32_16x16x32_bf16(
                    ahi.v, blo[nt].v, acc[mt][nt], 0, 0, 0);
                acc[mt][nt] = __builtin_amdgcn_mfma_f32_16x16x32_bf16(
                    alo.v, bhi[nt].v, acc[mt][nt], 0, 0, 0);
            }
        }
    }

    __syncthreads();
    float* cs = (float*)smem;
#pragma unroll
    for (int mt = 0; mt < MT; ++mt)
#pragma unroll
        for (int nt = 0; nt < NT; ++nt) {
            int nl  = wn * NT * 16 + nt * 16 + lm;
            int mb2 = wm * (MT * 16) + mt * 16 + q * 4;
#pragma unroll
            for (int r = 0; r < 4; ++r)
                cs[nl * 68 + mb2 + r] = acc[mt][nt][r];
        }
    __syncthreads();
    constexpr int EIT = NB * 64 / 256;
#pragma unroll
    for (int it = 0; it < EIT; ++it) {
        int idx = tid + 256 * it;
        int c = idx >> 6, m = idx & 63;
        int il = m >> LOG_W, jl = m & (W - 1);
        int oy = 2 * (il0 + il) + dy;
        int ox = 2 * jl + dx;
        float v = fmaxf(cs[c * 68 + m], 0.0f);
        size_t go = (((size_t)(nimg * Cout + c)) * (2 * Hh) + oy) * (2 * W) + ox;
        if (PACKO) ((unsigned*)y)[go] = pack_split(v);
        else       y[go] = v;
    }
}

// ================= direct convT (g4, tanh; unchanged) ======================
template<int Cin, int H, int W, int Cout, int COT, int ACT, int UNR>
__global__ void __launch_bounds__(256) convt4s2_k(
    const float* __restrict__ x, const float* __restrict__ w,
    const float* __restrict__ bias, float* __restrict__ y)
{
    constexpr int OH = 2 * H, OW = 2 * W, OWq = OW / 4;
    int id = blockIdx.x * 256 + threadIdx.x;
    int ox4 = id % OWq; int t = id / OWq;
    int oy  = t % OH;   t /= OH;
    int cog = t % (Cout / COT);
    int n   = t / (Cout / COT);
    int co0 = __builtin_amdgcn_readfirstlane(cog * COT);
    n       = __builtin_amdgcn_readfirstlane(n);

    int p   = (oy + 1) & 1;
    int iyA = (oy + 1 - p) >> 1;
    int iyB = iyA - 1;
    bool vA = (iyA < H);
    bool vB = (iyB >= 0);
    int iyAc = vA ? iyA : 0, iyBc = vB ? iyB : 0;

    int t0 = 2 * ox4;
    bool c0 = (t0 - 1 >= 0);
    bool c3 = (t0 + 2 <= W - 1);
    int j0 = c0 ? t0 - 1 : 0;
    int j3 = c3 ? t0 + 2 : 0;

    float acc[COT][4];
#pragma unroll
    for (int o = 0; o < COT; ++o) {
        float b = bias[co0 + o];
#pragma unroll
        for (int j = 0; j < 4; ++j) acc[o][j] = b;
    }

    const float* xn = x + (size_t)n * Cin * H * W;

#pragma unroll UNR
    for (int ci = 0; ci < Cin; ++ci) {
        const float* xc  = xn + (size_t)ci * (H * W);
        const float* xrA = xc + (size_t)iyAc * W;
        const float* xrB = xc + (size_t)iyBc * W;
        float a0 = (vA && c0) ? xrA[j0]     : 0.0f;
        float a1 =  vA        ? xrA[t0]     : 0.0f;
        float a2 =  vA        ? xrA[t0 + 1] : 0.0f;
        float a3 = (vA && c3) ? xrA[j3]     : 0.0f;
        float b0 = (vB && c0) ? xrB[j0]     : 0.0f;
        float b1 =  vB        ? xrB[t0]     : 0.0f;
        float b2 =  vB        ? xrB[t0 + 1] : 0.0f;
        float b3 = (vB && c3) ? xrB[j3]     : 0.0f;

        const float* wci = w + ((size_t)ci * Cout + co0) * 16;
#pragma unroll
        for (int o = 0; o < COT; ++o) {
            const float* wr = wci + (size_t)o * 16;
            float wA0 = wr[p * 4 + 0], wA1 = wr[p * 4 + 1];
            float wA2 = wr[p * 4 + 2], wA3 = wr[p * 4 + 3];
            float wB0 = wr[(p + 2) * 4 + 0], wB1 = wr[(p + 2) * 4 + 1];
            float wB2 = wr[(p + 2) * 4 + 2], wB3 = wr[(p + 2) * 4 + 3];
            acc[o][0] = fmaf(a1, wA1, acc[o][0]); acc[o][0] = fmaf(a0, wA3, acc[o][0]);
            acc[o][0] = fmaf(b1, wB1, acc[o][0]); acc[o][0] = fmaf(b0, wB3, acc[o][0]);
            acc[o][1] = fmaf(a2, wA0, acc[o][1]); acc[o][1] = fmaf(a1, wA2, acc[o][1]);
            acc[o][1] = fmaf(b2, wB0, acc[o][1]); acc[o][1] = fmaf(b1, wB2, acc[o][1]);
            acc[o][2] = fmaf(a2, wA1, acc[o][2]); acc[o][2] = fmaf(a1, wA3, acc[o][2]);
            acc[o][2] = fmaf(b2, wB1, acc[o][2]); acc[o][2] = fmaf(b1, wB3, acc[o][2]);
            acc[o][3] = fmaf(a3, wA0, acc[o][3]); acc[o][3] = fmaf(a2, wA2, acc[o][3]);
            acc[o][3] = fmaf(b3, wB0, acc[o][3]); acc[o][3] = fmaf(b2, wB2, acc[o][3]);
        }
    }

    int ox0 = ox4 * 4;
#pragma unroll
    for (int o = 0; o < COT; ++o) {
        float* yr = y + (((size_t)n * Cout + co0 + o) * OH + oy) * OW + ox0;
#pragma unroll
        for (int j = 0; j < 4; ++j) {
            float v = acc[o][j];
            yr[j] = (ACT == 0) ? fmaxf(v, 0.0f) : tanhf(v);
        }
    }
}

// =============================== quantizer =================================
__global__ void __launch_bounds__(256) embed_norms(
    const float* __restrict__ embed, float* __restrict__ norms)
{
    int c = blockIdx.x * 256 + threadIdx.x;
    const float* e = embed + (size_t)c * 512;
    float s = 0.0f;
    for (int k = 0; k < 512; ++k) s = fmaf(e[k], e[k], s);
    norms[c] = s;
}

__global__ void __launch_bounds__(256, 4) vq_argmin8v(
    const float* __restrict__ z, const float* __restrict__ et,
    const float* __restrict__ norms, int* __restrict__ out)
{
    constexpr int ZS = 516;
    int row0 = blockIdx.x * 8;
    int n    = row0 >> 8;
    int yx0  = row0 & 255;
    int tid  = threadIdx.x;

    __shared__ float zr[8 * ZS];

    const float* zn = z + ((size_t)n * 512) * 256;
#pragma unroll
    for (int it = 0; it < 4; ++it) {
        int i  = tid + 256 * it;
        int rq = i & 1, kc = i >> 1;
        float4 v = *(const float4*)&zn[(size_t)kc * 256 + yx0 + 4 * rq];
        zr[(4 * rq + 0) * ZS + kc] = v.x;
        zr[(4 * rq + 1) * ZS + kc] = v.y;
        zr[(4 * rq + 2) * ZS + kc] = v.z;
        zr[(4 * rq + 3) * ZS + kc] = v.w;
    }
    __syncthreads();

    f32x4 acc[8];
#pragma unroll
    for (int r = 0; r < 8; ++r) acc[r] = (f32x4){0.f, 0.f, 0.f, 0.f};

    const float* ebase = et + 4 * tid;
    f32x4 ev[4], fv[4];
#pragma unroll
    for (int j = 0; j < 4; ++j)
        ev[j] = *(const f32x4*)&ebase[(size_t)j * 1024];

#pragma unroll 1
    for (int k4 = 0; k4 < 128; ++k4) {
        int kn = (k4 + 1 < 128) ? k4 + 1 : 127;
#pragma unroll
        for (int j = 0; j < 4; ++j)
            fv[j] = *(const f32x4*)&ebase[(size_t)(4 * kn + j) * 1024];
#pragma unroll
        for (int r = 0; r < 8; ++r) {
            float4 zz = *(const float4*)&zr[r * ZS + 4 * k4];
            f32x4 a = acc[r];
            a += ev[0] * zz.x;
            a += ev[1] * zz.y;
            a += ev[2] * zz.z;
            a += ev[3] * zz.w;
            acc[r] = a;
        }
#pragma unroll
        for (int j = 0; j < 4; ++j) ev[j] = fv[j];
    }

    float4 nb = *(const float4*)&norms[4 * tid];
    float best[8]; int bi[8];
#pragma unroll
    for (int r = 0; r < 8; ++r) {
        float d0 = nb.x - 2.0f * acc[r][0];
        float d1 = nb.y - 2.0f * acc[r][1];
        float d2 = nb.z - 2.0f * acc[r][2];
        float d3 = nb.w - 2.0f * acc[r][3];
        float b = d0; int ix = 4 * tid;
        if (d1 < b) { b = d1; ix = 4 * tid + 1; }
        if (d2 < b) { b = d2; ix = 4 * tid + 2; }
        if (d3 < b) { b = d3; ix = 4 * tid + 3; }
        best[r] = b; bi[r] = ix;
    }

    __syncthreads();
    float* rbd = zr;
    int*   rbi = (int*)(zr + 2048);
#pragma unroll
    for (int r = 0; r < 8; ++r) {
        rbd[r * 256 + tid] = best[r];
        rbi[r * 256 + tid] = bi[r];
    }
    __syncthreads();
    for (int s = 128; s > 0; s >>= 1) {
        if (tid < s) {
#pragma unroll
            for (int r = 0; r < 8; ++r) {
                int i0 = r * 256 + tid;
                float od = rbd[i0 + s]; int oi = rbi[i0 + s];
                float md = rbd[i0];     int mi = rbi[i0];
                if (od < md || (od == md && oi < mi)) { rbd[i0] = od; rbi[i0] = oi; }
            }
        }
        __syncthreads();
    }
    if (tid < 8) out[row0 + tid] = rbi[tid * 256];
}

__global__ void __launch_bounds__(256) vq_gather_pack(
    const int* __restrict__ vidx, const float* __restrict__ embed,
    unsigned* __restrict__ zq)
{
    int i = blockIdx.x * 256 + threadIdx.x;
    int yx = i & 255;
    int t  = i >> 8;
    int c  = t & 511;
    int n  = t >> 9;
    int row = (n << 8) + yx;
    zq[i] = pack_split(embed[(size_t)vidx[row] * 512 + c]);
}

// ================================ launch ===================================
extern "C" void kernel_launch(void* const* d_in, const int* in_sizes, int n_in,
                              void* d_out, int out_size, void* d_ws, size_t ws_size,
                              hipStream_t stream)
{
    (void)in_sizes; (void)n_in; (void)out_size; (void)ws_size;
    const float* x     = (const float*)d_in[0];
    const float* ew1   = (const float*)d_in[1];
    const float* eb1   = (const float*)d_in[2];
    const float* ew2   = (const float*)d_in[3];
    const float* eb2   = (const float*)d_in[4];
    const float* ew3   = (const float*)d_in[5];
    const float* eb3   = (const float*)d_in[6];
    const float* ew4   = (const float*)d_in[7];
    const float* eb4   = (const float*)d_in[8];
    const float* dw1   = (const float*)d_in[9];
    const float* db1   = (const float*)d_in[10];
    const float* dw2   = (const float*)d_in[11];
    const float* db2   = (const float*)d_in[12];
    const float* dw3   = (const float*)d_in[13];
    const float* db3   = (const float*)d_in[14];
    const float* dw4   = (const float*)d_in[15];
    const float* db4   = (const float*)d_in[16];
    const float* embed = (const float*)d_in[17];
    float* out = (float*)d_out;

    // ---- workspace layout (u32 units). Identical to R16.
    unsigned* W0   = (unsigned*)d_ws;
    unsigned* h1p  = W0;
    unsigned* h2p  = W0 + 33554432;
    unsigned* xp1  = W0 + 33554432;
    unsigned* h3p  = W0;
    float*    z    = (float*)(W0 + 8388608);
    unsigned* zq   = W0 + 12582912;
    float*    P0   = (float*)(W0 + 16777216);
    float*    P1   = (float*)(W0 + 20971520);
    int*      vidx = (int*)(W0 + 29360128);
    float*    norms= (float*)(W0 + 29368320);
    float*    g3o  = (float*)h2p;

    // packed weights + transposed codebook live in d_out until g4 overwrites
    unsigned* wp2 = (unsigned*)d_out;             // 131,072
    unsigned* wp3 = wp2 + 131072;                 // 524,288
    unsigned* wp4 = wp2 + 655360;                 // 2,097,152
    unsigned* wq1 = wp2 + 2752512;                // 1,048,576
    unsigned* wq2 = wq1 + 1048576;                // 131,072
    unsigned* wq3 = wq2 + 131072;                 // 32,768
    float*    et  = (float*)(wq3 + 32768);        // 524,288 (512x1024)
    unsigned* wp1 = (unsigned*)(et + 524288);     // 4,096 (64x64 padded)

    dim3 b256(256);

    // ---- pre-pass ----
    pack_tensor<<<dim3(512),  b256, 0, stream>>>(ew2, wp2, 131072);
    pack_tensor<<<dim3(2048), b256, 0, stream>>>(ew3, wp3, 524288);
    pack_tensor<<<dim3(8192), b256, 0, stream>>>(ew4, wp4, 2097152);
    pack_w1<<<dim3(16), b256, 0, stream>>>(ew1, wp1);
    pack_tensor<<<dim3(24576), b256, 0, stream>>>(x, xp1, 6291456);
    repack_wt_planes<512, 128><<<dim3(4096), b256, 0, stream>>>(dw1, wq1);
    repack_wt_planes<128,  64><<<dim3(512),  b256, 0, stream>>>(dw2, wq2);
    repack_wt_planes< 64,  32><<<dim3(128),  b256, 0, stream>>>(dw3, wq3);
    embed_transpose<<<dim3(2048), b256, 0, stream>>>(embed, et);

    // ---- encoder ----
    conv4s2_mfma_g<4, 3, 256, 256, 64, 4, 1, 1><<<dim3(8192), b256, 0, stream>>>(
        xp1, wp1, eb1, (float*)h1p);                       // h1 (packed)
    conv4s2_mfma<64, 128, 128, 128, 128, 1><<<dim3(2048), b256, 0, stream>>>(
        h1p, wp2, eb2, (float*)h2p);                       // h2 (packed)
    conv4s2_mfma<128, 64, 64, 256, 128, 1><<<dim3(1024), b256, 0, stream>>>(
        h2p, wp3, eb3, (float*)h3p);                       // h3 (packed)
    conv4s2_mfma<256, 32, 32, 512, 64, 0><<<dim3(1024), b256, 0, stream>>>(
        h3p, wp4, eb4, z);                                 // z (fp32)

    // ---- quantizer ----
    embed_norms<<<dim3(4), b256, 0, stream>>>(embed, norms);
    vq_argmin8v<<<dim3(1024), b256, 0, stream>>>(z, et, norms, vidx);
    vq_gather_pack<<<dim3(16384), b256, 0, stream>>>(vidx, embed, zq);

    // ---- decoder (MFMA parity-GEMM convT) ----
    convt4s2_mfma<512, 16, 16, 128, 4, 2, 1><<<dim3(4 * 128), b256, 0, stream>>>(
        zq, wq1, db1, P0);                                 // P0 (packed)
    convt4s2_mfma<128, 32, 32, 64, 4, 1, 1><<<dim3(4 * 512), b256, 0, stream>>>(
        (const unsigned*)P0, wq2, db2, P1);                // P1 (packed)
    convt4s2_mfma<64, 64, 64, 32, 2, 1, 0><<<dim3(4 * 2048), b256, 0, stream>>>(
        (const unsigned*)P1, wq3, db3, g3o);               // g3o (fp32)
    convt4s2_k<32, 128, 128, 3, 3, 1, 2><<<dim3(2048), b256, 0, stream>>>(
        g3o, dw4, db4, out);                               // tanh -> d_out
}

// Round 12
// 1062.074 us; speedup vs baseline: 1.1349x; 1.0441x over previous
//
#include <hip/hip_runtime.h>
#include <math.h>

// ---------------------------------------------------------------------------
// VQ-VAE forward. Round 19: R18 + explicit v_perm_b32 fragment repack.
// R18 counters (conv2: VALUBusy 53%, MfmaUtil 22%) match a model where each
// hi/lo repack u32 costs 3 VALU ops (and/shift/or) -> ~576 VALU cyc vs 120
// MFMA cyc per chunk. Both repack patterns are single v_perm_b32 ops:
//   (e0&0xffff)|(e1<<16)      = perm(e1,e0,0x05040100)
//   (e0>>16)|(e1&0xffff0000)  = perm(e1,e0,0x07060302)
// Applied to conv/conv_g A+B frags and convT afrag. Bit-identical numerics.
// Everything else exactly R18 (best: 1108.9us).
// ---------------------------------------------------------------------------

typedef __attribute__((ext_vector_type(8))) short bf16x8;
typedef __attribute__((ext_vector_type(4))) float f32x4;
union FragU { unsigned u[4]; bf16x8 v; };

__device__ __forceinline__ unsigned pk_lo(unsigned e0, unsigned e1) {
    // (e0 & 0xffff) | (e1 << 16)
    return __builtin_amdgcn_perm(e1, e0, 0x05040100u);
}
__device__ __forceinline__ unsigned pk_hi(unsigned e0, unsigned e1) {
    // (e0 >> 16) | (e1 & 0xffff0000)
    return __builtin_amdgcn_perm(e1, e0, 0x07060302u);
}

__device__ __forceinline__ unsigned bf16_rne(unsigned u) {
    return (u + 0x7FFFu + ((u >> 16) & 1u)) >> 16;
}
// pack fp32 -> u32: low16 = bf16(v), high16 = bf16(v - bf16(v))
__device__ __forceinline__ unsigned pack_split(float v) {
    unsigned u = __builtin_bit_cast(unsigned, v);
    unsigned hi = bf16_rne(u);
    float hif = __builtin_bit_cast(float, hi << 16);
    float r = v - hif;
    unsigned lo = bf16_rne(__builtin_bit_cast(unsigned, r));
    return hi | (lo << 16);
}

__global__ void __launch_bounds__(256) pack_tensor(
    const float* __restrict__ s, unsigned* __restrict__ d, int n)
{
    int i = blockIdx.x * 256 + threadIdx.x;
    if (i < n) d[i] = pack_split(s[i]);
}

// conv1 weights (64,3,4,4) -> padded packed [64][64] (k>=48 zero)
__global__ void __launch_bounds__(256) pack_w1(
    const float* __restrict__ w, unsigned* __restrict__ wq)
{
    int idx = blockIdx.x * 256 + threadIdx.x;
    if (idx >= 64 * 64) return;
    int k = idx & 63, oc = idx >> 6;
    float v = (k < 48) ? w[oc * 48 + k] : 0.0f;
    wq[idx] = pack_split(v);
}

// ConvTranspose weights (torch Cin,Cout,4,4) -> pair-planes
// [2][par][Cout][K/2], K = Cin*4, k = ci*4 + (2r+s), par = dy*2+dx.
template<int Cin, int Cout>
__global__ void __launch_bounds__(256) repack_wt_planes(
    const float* __restrict__ w, unsigned* __restrict__ wq)
{
    constexpr int K = Cin * 4, K2 = K / 2;
    constexpr int TOT = 2 * 4 * Cout * K2;
    int idx = blockIdx.x * 256 + threadIdx.x;
    if (idx >= TOT) return;
    int kp   = idx % K2;
    int rest = idx / K2;
    int co   = rest % Cout;
    rest    /= Cout;
    int par  = rest & 3;
    int p    = rest >> 2;
    int dy = par >> 1, dx = par & 1;
    unsigned u01[2];
#pragma unroll
    for (int e = 0; e < 2; ++e) {
        int k = 2 * kp + e;
        int t = k & 3, ci = k >> 2;
        int r = t >> 1, s = t & 1;
        int ky = 3 - dy - 2 * r;
        int kx = 3 - dx - 2 * s;
        u01[e] = pack_split(w[(((size_t)ci * Cout + co) * 4 + ky) * 4 + kx]);
    }
    wq[idx] = (p == 0) ? pk_lo(u01[0], u01[1]) : pk_hi(u01[0], u01[1]);
}

// transpose codebook: embed[1024][512] -> et[512][1024]
__global__ void __launch_bounds__(256) embed_transpose(
    const float* __restrict__ embed, float* __restrict__ et)
{
    int idx = blockIdx.x * 256 + threadIdx.x;
    int c = idx & 1023, k = idx >> 10;
    et[idx] = embed[(size_t)c * 512 + k];
}

// ================= MFMA conv k=4 s=2 p=1 + ReLU (implicit GEMM) ============
// R13 structure; repack via v_perm. NB = oc per block (64 or 128).
template<int Cin, int H, int W, int Cout, int NB, int PACKO>
__global__ void __launch_bounds__(256) conv4s2_mfma(
    const unsigned* __restrict__ xp, const unsigned* __restrict__ wp,
    const float* __restrict__ bias, float* __restrict__ y)
{
    constexpr int OH = H / 2, OW = W / 2;
    constexpr int LOG_OW = (OW == 64) ? 6 : (OW == 32) ? 5 : 4;
    constexpr int R   = 64 / OW;
    constexpr int RT  = 2 * R + 2;
    constexpr int CS  = W + 2;
    constexpr int XEL = 2 * RT * CS;
    constexpr int XIT = (XEL + 255) / 256;
    constexpr int K   = Cin * 16;
    constexpr int NC  = Cin / 2;
    constexpr int NT  = NB / 64;            // oc 16-tiles per wave
    constexpr int WIT = NB / 8;             // B-load iterations
    constexpr int MBC = 32 * OH * OW / 64;
    constexpr int XPAD = (XEL + 7) & ~7;
    constexpr int SM1 = XPAD + NB * 36;
    constexpr int SM2 = NB * 68;
    constexpr int SMEM = SM1 > SM2 ? SM1 : SM2;

    __shared__ unsigned smem[SMEM];
    unsigned* raw = smem;
    unsigned* wb  = smem + XPAD;

    int bid = blockIdx.x;
    int mb = bid % MBC, ng = bid / MBC;
    int oc0 = ng * NB;
    int m0 = mb * 64;
    int nimg = m0 / (OH * OW);
    int sp0 = m0 % (OH * OW);
    int oyb = sp0 >> LOG_OW;

    int tid  = threadIdx.x;
    int lane = tid & 63, wv = tid >> 6;
    int lm = lane & 15, q = lane >> 4;
    int n0w = wv * 16 * NT;

    const unsigned* xbase = xp + (size_t)nimg * Cin * H * W;

    int  goff[XIT];
    bool gok[XIT];
#pragma unroll
    for (int s = 0; s < XIT; ++s) {
        int i = tid + 256 * s;
        goff[s] = 0; gok[s] = false;
        if (i < XEL) {
            int lc = i % CS;
            int t2 = i / CS;
            int lr = t2 % RT;
            int c  = t2 / RT;
            int gr = 2 * oyb - 1 + lr;
            int gc = lc - 1;
            bool ok = ((unsigned)gr < (unsigned)H) && ((unsigned)gc < (unsigned)W);
            goff[s] = ok ? (c * H * W + gr * W + gc) : 0;
            gok[s]  = ok;
        }
    }
    const unsigned* wbase = wp + (size_t)(oc0 + (tid >> 5)) * K + (tid & 31);
    int wlds0 = (tid >> 5) * 36 + (tid & 31);

    f32x4 acc[4][NT];
#pragma unroll
    for (int nt = 0; nt < NT; ++nt) {
        float b = bias[oc0 + n0w + nt * 16 + lm];
#pragma unroll
        for (int mt = 0; mt < 4; ++mt)
#pragma unroll
            for (int r = 0; r < 4; ++r) acc[mt][nt][r] = b;
    }

    unsigned pfa[XIT];
    unsigned pfb[WIT];

    auto load_chunk = [&](int ch) {
        const unsigned* cb = xbase + (size_t)(ch * 2) * (H * W);
#pragma unroll
        for (int s = 0; s < XIT; ++s) {
            unsigned v = 0;
            if (gok[s]) v = cb[goff[s]];
            pfa[s] = v;
        }
        const unsigned* wc = wbase + ch * 32;
#pragma unroll
        for (int s = 0; s < WIT; ++s) pfb[s] = wc[(size_t)s * 8 * K];
    };
    auto store_chunk = [&]() {
#pragma unroll
        for (int s = 0; s < XIT; ++s) {
            int i = tid + 256 * s;
            if (i < XEL) raw[i] = pfa[s];
        }
#pragma unroll
        for (int s = 0; s < WIT; ++s) wb[wlds0 + s * 288] = pfb[s];
    };

    load_chunk(0);
#pragma unroll 1
    for (int ch = 0; ch < NC; ++ch) {
        __syncthreads();
        store_chunk();
        __syncthreads();
        if (ch + 1 < NC) load_chunk(ch + 1);

        FragU bhi[NT], blo[NT];
#pragma unroll
        for (int nt = 0; nt < NT; ++nt) {
            const unsigned* bp = &wb[(n0w + nt * 16 + lm) * 36 + q * 8];
            uint4 p0 = *(const uint4*)bp;
            uint4 p1 = *(const uint4*)(bp + 4);
            bhi[nt].u[0] = pk_lo(p0.x, p0.y);
            bhi[nt].u[1] = pk_lo(p0.z, p0.w);
            bhi[nt].u[2] = pk_lo(p1.x, p1.y);
            bhi[nt].u[3] = pk_lo(p1.z, p1.w);
            blo[nt].u[0] = pk_hi(p0.x, p0.y);
            blo[nt].u[1] = pk_hi(p0.z, p0.w);
            blo[nt].u[2] = pk_hi(p1.x, p1.y);
            blo[nt].u[3] = pk_hi(p1.z, p1.w);
        }
#pragma unroll
        for (int mt = 0; mt < 4; ++mt) {
            int m = mt * 16 + lm;
            int oyl = m >> LOG_OW, oxl = m & (OW - 1);
            int c = q >> 1, rb = 2 * oyl + (q & 1) * 2;
            const unsigned* rp = &raw[(c * RT + rb) * CS + 2 * oxl];
            uint2 a0 = *(const uint2*)rp;
            uint2 a1 = *(const uint2*)(rp + 2);
            uint2 a2 = *(const uint2*)(rp + CS);
            uint2 a3 = *(const uint2*)(rp + CS + 2);
            FragU ahi, alo;
            ahi.u[0] = pk_lo(a0.x, a0.y);
            ahi.u[1] = pk_lo(a1.x, a1.y);
            ahi.u[2] = pk_lo(a2.x, a2.y);
            ahi.u[3] = pk_lo(a3.x, a3.y);
            alo.u[0] = pk_hi(a0.x, a0.y);
            alo.u[1] = pk_hi(a1.x, a1.y);
            alo.u[2] = pk_hi(a2.x, a2.y);
            alo.u[3] = pk_hi(a3.x, a3.y);
#pragma unroll
            for (int nt = 0; nt < NT; ++nt) {
                acc[mt][nt] = __builtin_amdgcn_mfma_f32_16x16x32_bf16(
                    ahi.v, bhi[nt].v, acc[mt][nt], 0, 0, 0);
                acc[mt][nt] = __builtin_amdgcn_mfma_f32_16x16x32_bf16(
                    ahi.v, blo[nt].v, acc[mt][nt], 0, 0, 0);
                acc[mt][nt] = __builtin_amdgcn_mfma_f32_16x16x32_bf16(
                    alo.v, bhi[nt].v, acc[mt][nt], 0, 0, 0);
            }
        }
    }

    __syncthreads();
    float* cs = (float*)smem;
#pragma unroll
    for (int mt = 0; mt < 4; ++mt)
#pragma unroll
        for (int nt = 0; nt < NT; ++nt) {
            int nl = n0w + nt * 16 + lm;
#pragma unroll
            for (int r = 0; r < 4; ++r)
                cs[nl * 68 + mt * 16 + q * 4 + r] = acc[mt][nt][r];
        }
    __syncthreads();
    {
        constexpr int QT = 256 / NB;            // threads per channel
        constexpr int MQ = 64 / QT;             // m per thread
        int nl = tid / QT, qt = tid % QT;
        size_t gb = ((size_t)(nimg * Cout + oc0 + nl)) * (OH * OW) + sp0 + qt * MQ;
#pragma unroll
        for (int i2 = 0; i2 < MQ / 4; ++i2) {
            float4 v = *(float4*)&cs[nl * 68 + qt * MQ + 4 * i2];
            v.x = fmaxf(v.x, 0.0f); v.y = fmaxf(v.y, 0.0f);
            v.z = fmaxf(v.z, 0.0f); v.w = fmaxf(v.w, 0.0f);
            if (PACKO) {
                uint4 p;
                p.x = pack_split(v.x); p.y = pack_split(v.y);
                p.z = pack_split(v.z); p.w = pack_split(v.w);
                *(uint4*)((unsigned*)y + gb + 4 * i2) = p;
            } else {
                *(float4*)(y + gb + 4 * i2) = v;
            }
        }
    }
}

// ========== generalized MFMA conv (conv1) ==================================
template<int Cin, int CINR, int H, int W, int Cout, int MT, int NT, int PACKO>
__global__ void __launch_bounds__(256) conv4s2_mfma_g(
    const unsigned* __restrict__ xp, const unsigned* __restrict__ wp,
    const float* __restrict__ bias, float* __restrict__ y)
{
    constexpr int OH = H / 2, OW = W / 2;
    constexpr int OWB = (OW >= 64) ? 64 : OW;
    constexpr int LOG_OWB = (OWB == 64) ? 6 : (OWB == 32) ? 5 : 4;
    constexpr int LOG_OW  = (OW == 128) ? 7 : (OW == 64) ? 6 : (OW == 32) ? 5 : 4;
    constexpr int R   = 64 / OWB;
    constexpr int RT  = 2 * R + 2;
    constexpr int CS  = 2 * OWB + 2;
    constexpr int XEL = 2 * RT * CS;
    constexpr int XIT = (XEL + 255) / 256;
    constexpr int K   = Cin * 16;
    constexpr int NC  = Cin / 2;
    constexpr int NB  = Cout;
    constexpr int WIT = NB / 8;
    constexpr int WN  = Cout / (16 * NT);
    constexpr int WM  = 4 / WN;
    static_assert(WM * MT * 16 == 64, "M tiling");
    static_assert(WN * NT * 16 == Cout, "N tiling");
    constexpr int MBC = 32 * OH * OW / 64;
    constexpr int XPAD = (XEL + 7) & ~7;
    constexpr int SM1 = XPAD + NB * 36;
    constexpr int SM2 = NB * 68;
    constexpr int SMEM = SM1 > SM2 ? SM1 : SM2;

    __shared__ unsigned smem[SMEM];
    unsigned* raw = smem;
    unsigned* wb  = smem + XPAD;

    int bid = blockIdx.x;
    int mb = bid % MBC, ng = bid / MBC;
    int oc0 = ng * NB;
    int m0 = mb * 64;
    int nimg = m0 / (OH * OW);
    int sp0 = m0 % (OH * OW);
    int oyb = sp0 >> LOG_OW;
    int oxb = sp0 & (OW - 1);

    int tid  = threadIdx.x;
    int lane = tid & 63, wv = tid >> 6;
    int lm = lane & 15, q = lane >> 4;
    int wm = wv / WN, wn = wv % WN;

    const unsigned* xbase = xp + (size_t)nimg * CINR * H * W;

    int  goff[XIT];
    bool gok[XIT];
    int  cidx[XIT];
#pragma unroll
    for (int s = 0; s < XIT; ++s) {
        int i = tid + 256 * s;
        goff[s] = 0; gok[s] = false; cidx[s] = 0;
        if (i < XEL) {
            int lc = i % CS;
            int t2 = i / CS;
            int lr = t2 % RT;
            int c  = t2 / RT;
            int gr = 2 * oyb - 1 + lr;
            int gc = 2 * oxb - 1 + lc;
            bool ok = ((unsigned)gr < (unsigned)H) && ((unsigned)gc < (unsigned)W);
            goff[s] = ok ? (c * H * W + gr * W + gc) : 0;
            gok[s]  = ok;
            cidx[s] = c;
        }
    }
    const unsigned* wbase = wp + (size_t)(oc0 + (tid >> 5)) * K + (tid & 31);
    int wlds0 = (tid >> 5) * 36 + (tid & 31);

    f32x4 acc[MT][NT];
#pragma unroll
    for (int nt = 0; nt < NT; ++nt) {
        float b = bias[oc0 + wn * NT * 16 + nt * 16 + lm];
#pragma unroll
        for (int mt = 0; mt < MT; ++mt)
#pragma unroll
            for (int r = 0; r < 4; ++r) acc[mt][nt][r] = b;
    }

    unsigned pfa[XIT];
    unsigned pfb[WIT];

    auto load_chunk = [&](int ch) {
        const unsigned* cb = xbase + (size_t)(ch * 2) * (H * W);
#pragma unroll
        for (int s = 0; s < XIT; ++s) {
            unsigned v = 0;
            bool okc = (2 * ch + cidx[s]) < CINR;
            if (gok[s] && okc) v = cb[goff[s]];
            pfa[s] = v;
        }
        const unsigned* wc = wbase + ch * 32;
#pragma unroll
        for (int s = 0; s < WIT; ++s) pfb[s] = wc[(size_t)s * 8 * K];
    };
    auto store_chunk = [&]() {
#pragma unroll
        for (int s = 0; s < XIT; ++s) {
            int i = tid + 256 * s;
            if (i < XEL) raw[i] = pfa[s];
        }
#pragma unroll
        for (int s = 0; s < WIT; ++s) wb[wlds0 + s * 288] = pfb[s];
    };

    load_chunk(0);
#pragma unroll 1
    for (int ch = 0; ch < NC; ++ch) {
        __syncthreads();
        store_chunk();
        __syncthreads();
        if (ch + 1 < NC) load_chunk(ch + 1);

        FragU bhi[NT], blo[NT];
#pragma unroll
        for (int nt = 0; nt < NT; ++nt) {
            const unsigned* bp = &wb[(wn * NT * 16 + nt * 16 + lm) * 36 + q * 8];
            uint4 p0 = *(const uint4*)bp;
            uint4 p1 = *(const uint4*)(bp + 4);
            bhi[nt].u[0] = pk_lo(p0.x, p0.y);
            bhi[nt].u[1] = pk_lo(p0.z, p0.w);
            bhi[nt].u[2] = pk_lo(p1.x, p1.y);
            bhi[nt].u[3] = pk_lo(p1.z, p1.w);
            blo[nt].u[0] = pk_hi(p0.x, p0.y);
            blo[nt].u[1] = pk_hi(p0.z, p0.w);
            blo[nt].u[2] = pk_hi(p1.x, p1.y);
            blo[nt].u[3] = pk_hi(p1.z, p1.w);
        }
#pragma unroll
        for (int mt = 0; mt < MT; ++mt) {
            int m = wm * (MT * 16) + mt * 16 + lm;
            int oyl = m >> LOG_OWB, oxl = m & (OWB - 1);
            int c = q >> 1, rb = 2 * oyl + (q & 1) * 2;
            const unsigned* rp = &raw[(c * RT + rb) * CS + 2 * oxl];
            uint2 a0 = *(const uint2*)rp;
            uint2 a1 = *(const uint2*)(rp + 2);
            uint2 a2 = *(const uint2*)(rp + CS);
            uint2 a3 = *(const uint2*)(rp + CS + 2);
            FragU ahi, alo;
            ahi.u[0] = pk_lo(a0.x, a0.y);
            ahi.u[1] = pk_lo(a1.x, a1.y);
            ahi.u[2] = pk_lo(a2.x, a2.y);
            ahi.u[3] = pk_lo(a3.x, a3.y);
            alo.u[0] = pk_hi(a0.x, a0.y);
            alo.u[1] = pk_hi(a1.x, a1.y);
            alo.u[2] = pk_hi(a2.x, a2.y);
            alo.u[3] = pk_hi(a3.x, a3.y);
#pragma unroll
            for (int nt = 0; nt < NT; ++nt) {
                acc[mt][nt] = __builtin_amdgcn_mfma_f32_16x16x32_bf16(
                    ahi.v, bhi[nt].v, acc[mt][nt], 0, 0, 0);
                acc[mt][nt] = __builtin_amdgcn_mfma_f32_16x16x32_bf16(
                    ahi.v, blo[nt].v, acc[mt][nt], 0, 0, 0);
                acc[mt][nt] = __builtin_amdgcn_mfma_f32_16x16x32_bf16(
                    alo.v, bhi[nt].v, acc[mt][nt], 0, 0, 0);
            }
        }
    }

    __syncthreads();
    float* cs = (float*)smem;
#pragma unroll
    for (int mt = 0; mt < MT; ++mt)
#pragma unroll
        for (int nt = 0; nt < NT; ++nt) {
            int nl  = wn * NT * 16 + nt * 16 + lm;
            int mb2 = wm * (MT * 16) + mt * 16 + q * 4;
#pragma unroll
            for (int r = 0; r < 4; ++r)
                cs[nl * 68 + mb2 + r] = acc[mt][nt][r];
        }
    __syncthreads();
    {
        constexpr int QT = 256 / NB;
        constexpr int MQ = 64 / QT;
        int nl = tid / QT, qt = tid % QT;
        size_t gb = ((size_t)(nimg * Cout + oc0 + nl)) * (OH * OW) + sp0 + qt * MQ;
#pragma unroll
        for (int i2 = 0; i2 < MQ / 4; ++i2) {
            float4 v = *(float4*)&cs[nl * 68 + qt * MQ + 4 * i2];
            v.x = fmaxf(v.x, 0.0f); v.y = fmaxf(v.y, 0.0f);
            v.z = fmaxf(v.z, 0.0f); v.w = fmaxf(v.w, 0.0f);
            if (PACKO) {
                uint4 p;
                p.x = pack_split(v.x); p.y = pack_split(v.y);
                p.z = pack_split(v.z); p.w = pack_split(v.w);
                *(uint4*)((unsigned*)y + gb + 4 * i2) = p;
            } else {
                *(float4*)(y + gb + 4 * i2) = v;
            }
        }
    }
}

// ============ MFMA ConvTranspose (parity GEMM; pair-plane B) ===============
template<int Cin, int Hh, int Wh, int Cout, int MT, int NT, int PACKO>
__global__ void __launch_bounds__(256) convt4s2_mfma(
    const unsigned* __restrict__ xp, const unsigned* __restrict__ wq,
    const float* __restrict__ bias, float* __restrict__ y)
{
    constexpr int W = Wh;
    constexpr int LOG_W = (W == 64) ? 6 : (W == 32) ? 5 : 4;
    constexpr int R   = 64 / W;
    constexpr int RT  = R + 1;
    constexpr int CS  = W + 2;
    constexpr int XEL = 8 * RT * CS;
    constexpr int XIT = (XEL + 255) / 256;
    constexpr int K   = Cin * 4;
    constexpr int K2  = K / 2;
    constexpr int NC  = Cin / 8;
    constexpr int NB  = Cout;
    constexpr int WR  = NB / 16;
    constexpr int WIT = NB / 8;
    constexpr int WN  = Cout / (16 * NT);
    constexpr int WM  = 4 / WN;
    static_assert(WM * MT * 16 == 64, "M tiling");
    static_assert(WN * NT * 16 == Cout, "N tiling");
    constexpr int MBC = 32 * Hh * W / 64;
    constexpr int XPAD = (XEL + 7) & ~7;
    constexpr int OFF_WH = XPAD;
    constexpr int OFF_WL = OFF_WH + NB * 20;
    constexpr int OFF_AH = OFF_WL + NB * 20;
    constexpr int OFF_AL = OFF_AH + 64 * 20;
    constexpr int SM1 = OFF_AL + 64 * 20;
    constexpr int SM2 = NB * 68;
    constexpr int SMEM = SM1 > SM2 ? SM1 : SM2;

    __shared__ unsigned smem[SMEM];
    unsigned* raw = smem;
    unsigned* wbh = smem + OFF_WH;
    unsigned* wbl = smem + OFF_WL;
    unsigned* afh = smem + OFF_AH;
    unsigned* afl = smem + OFF_AL;

    int bid = blockIdx.x;
    int mb  = bid % MBC;
    int par = bid / MBC;
    int dy = par >> 1, dx = par & 1;

    int m0   = mb * 64;
    int nimg = m0 / (Hh * W);
    int sp0  = m0 % (Hh * W);
    int il0  = sp0 >> LOG_W;

    int tid = threadIdx.x;
    int lane = tid & 63, wv = tid >> 6;
    int lm = lane & 15, q = lane >> 4;
    int wm = wv / WN, wn = wv % WN;

    const unsigned* xbase = xp + (size_t)nimg * Cin * Hh * W;

    int  goff[XIT];
    bool gok[XIT];
#pragma unroll
    for (int s = 0; s < XIT; ++s) {
        int i = tid + 256 * s;
        goff[s] = 0; gok[s] = false;
        if (i < XEL) {
            int lc = i % CS;
            int t2 = i / CS;
            int lr = t2 % RT;
            int c  = t2 / RT;
            int gr = il0 - 1 + dy + lr;
            int gc = lc - 1;
            bool ok = ((unsigned)gr < (unsigned)Hh) && ((unsigned)gc < (unsigned)W);
            goff[s] = ok ? (c * Hh * W + gr * W + gc) : 0;
            gok[s]  = ok;
        }
    }
    // B loader: plane stride = 4*Cout*K2 (planes outermost)
    const unsigned* wbase_h = wq + (size_t)(par * Cout + (tid >> 4)) * K2 + (tid & 15);
    const unsigned* wbase_l = wbase_h + (size_t)4 * Cout * K2;
    int wlds0 = (tid >> 4) * 20 + (tid & 15);

    f32x4 acc[MT][NT];
#pragma unroll
    for (int nt = 0; nt < NT; ++nt) {
        float b = bias[wn * NT * 16 + nt * 16 + lm];
#pragma unroll
        for (int mt = 0; mt < MT; ++mt)
#pragma unroll
            for (int r = 0; r < 4; ++r) acc[mt][nt][r] = b;
    }

    unsigned pfa[XIT];
    unsigned pfb[WIT];

    auto load_chunk = [&](int ch) {
        const unsigned* cb = xbase + (size_t)(ch * 8) * (Hh * W);
#pragma unroll
        for (int s = 0; s < XIT; ++s) {
            unsigned v = 0;
            if (gok[s]) v = cb[goff[s]];
            pfa[s] = v;
        }
        const unsigned* wch = wbase_h + ch * 16;
        const unsigned* wcl = wbase_l + ch * 16;
#pragma unroll
        for (int s = 0; s < WR; ++s) {
            pfb[2 * s]     = wch[(size_t)s * 16 * K2];
            pfb[2 * s + 1] = wcl[(size_t)s * 16 * K2];
        }
    };
    auto store_chunk = [&]() {
#pragma unroll
        for (int s = 0; s < XIT; ++s) {
            int i = tid + 256 * s;
            if (i < XEL) raw[i] = pfa[s];
        }
#pragma unroll
        for (int s = 0; s < WR; ++s) {
            wbh[wlds0 + s * 16 * 20] = pfb[2 * s];
            wbl[wlds0 + s * 16 * 20] = pfb[2 * s + 1];
        }
    };

    load_chunk(0);
#pragma unroll 1
    for (int ch = 0; ch < NC; ++ch) {
        __syncthreads();
        store_chunk();
        __syncthreads();
        {
            int m = tid >> 2, blk = tid & 3;
            int il = m >> LOG_W, jl = m & (W - 1);
            unsigned h[4], l[4];
#pragma unroll
            for (int j = 0; j < 4; ++j) {
                int kp = blk * 4 + j;
                int cl = kp >> 1, r = kp & 1;
                int ro = (cl * RT + il + r) * CS + jl + dx;
                unsigned r0 = raw[ro], r1 = raw[ro + 1];
                h[j] = pk_lo(r0, r1);
                l[j] = pk_hi(r0, r1);
            }
            uint4 vh; vh.x = h[0]; vh.y = h[1]; vh.z = h[2]; vh.w = h[3];
            uint4 vl; vl.x = l[0]; vl.y = l[1]; vl.z = l[2]; vl.w = l[3];
            *(uint4*)&afh[m * 20 + blk * 4] = vh;
            *(uint4*)&afl[m * 20 + blk * 4] = vl;
        }
        if (ch + 1 < NC) load_chunk(ch + 1);
        __syncthreads();

        FragU bhi[NT], blo[NT];
#pragma unroll
        for (int nt = 0; nt < NT; ++nt) {
            int oc = wn * NT * 16 + nt * 16 + lm;
            uint4 th = *(const uint4*)&wbh[oc * 20 + q * 4];
            uint4 tl = *(const uint4*)&wbl[oc * 20 + q * 4];
            bhi[nt].u[0] = th.x; bhi[nt].u[1] = th.y;
            bhi[nt].u[2] = th.z; bhi[nt].u[3] = th.w;
            blo[nt].u[0] = tl.x; blo[nt].u[1] = tl.y;
            blo[nt].u[2] = tl.z; blo[nt].u[3] = tl.w;
        }
#pragma unroll
        for (int mt = 0; mt < MT; ++mt) {
            int ml = wm * (MT * 16) + mt * 16 + lm;
            uint4 ah = *(const uint4*)&afh[ml * 20 + q * 4];
            uint4 al = *(const uint4*)&afl[ml * 20 + q * 4];
            FragU ahi, alo;
            ahi.u[0] = ah.x; ahi.u[1] = ah.y; ahi.u[2] = ah.z; ahi.u[3] = ah.w;
            alo.u[0] = al.x; alo.u[1] = al.y; alo.u[2] = al.z; alo.u[3] = al.w;
#pragma unroll
            for (int nt = 0; nt < NT; ++nt) {
                acc[mt][nt] = __builtin_amdgcn_mfma_f32_16x16x32_bf16(
                    ahi.v, bhi[nt].v, acc[mt][nt], 0, 0, 0);
                acc[mt][nt] = __builtin_amdgcn_mfma_f32_16x16x32_bf16(
                    ahi.v, blo[nt].v, acc[mt][nt], 0, 0, 0);
                acc[mt][nt] = __builtin_amdgcn_mfma_f32_16x16x32_bf16(
                    alo.v, bhi[nt].v, acc[mt][nt], 0, 0, 0);
            }
        }
    }

    __syncthreads();
    float* cs = (float*)smem;
#pragma unroll
    for (int mt = 0; mt < MT; ++mt)
#pragma unroll
        for (int nt = 0; nt < NT; ++nt) {
            int nl  = wn * NT * 16 + nt * 16 + lm;
            int mb2 = wm * (MT * 16) + mt * 16 + q * 4;
#pragma unroll
            for (int r = 0; r < 4; ++r)
                cs[nl * 68 + mb2 + r] = acc[mt][nt][r];
        }
    __syncthreads();
    constexpr int EIT = NB * 64 / 256;
#pragma unroll
    for (int it = 0; it < EIT; ++it) {
        int idx = tid + 256 * it;
        int c = idx >> 6, m = idx & 63;
        int il = m >> LOG_W, jl = m & (W - 1);
        int oy = 2 * (il0 + il) + dy;
        int ox = 2 * jl + dx;
        float v = fmaxf(cs[c * 68 + m], 0.0f);
        size_t go = (((size_t)(nimg * Cout + c)) * (2 * Hh) + oy) * (2 * W) + ox;
        if (PACKO) ((unsigned*)y)[go] = pack_split(v);
        else       y[go] = v;
    }
}

// ================= direct convT (g4, tanh; unchanged) ======================
template<int Cin, int H, int W, int Cout, int COT, int ACT, int UNR>
__global__ void __launch_bounds__(256) convt4s2_k(
    const float* __restrict__ x, const float* __restrict__ w,
    const float* __restrict__ bias, float* __restrict__ y)
{
    constexpr int OH = 2 * H, OW = 2 * W, OWq = OW / 4;
    int id = blockIdx.x * 256 + threadIdx.x;
    int ox4 = id % OWq; int t = id / OWq;
    int oy  = t % OH;   t /= OH;
    int cog = t % (Cout / COT);
    int n   = t / (Cout / COT);
    int co0 = __builtin_amdgcn_readfirstlane(cog * COT);
    n       = __builtin_amdgcn_readfirstlane(n);

    int p   = (oy + 1) & 1;
    int iyA = (oy + 1 - p) >> 1;
    int iyB = iyA - 1;
    bool vA = (iyA < H);
    bool vB = (iyB >= 0);
    int iyAc = vA ? iyA : 0, iyBc = vB ? iyB : 0;

    int t0 = 2 * ox4;
    bool c0 = (t0 - 1 >= 0);
    bool c3 = (t0 + 2 <= W - 1);
    int j0 = c0 ? t0 - 1 : 0;
    int j3 = c3 ? t0 + 2 : 0;

    float acc[COT][4];
#pragma unroll
    for (int o = 0; o < COT; ++o) {
        float b = bias[co0 + o];
#pragma unroll
        for (int j = 0; j < 4; ++j) acc[o][j] = b;
    }

    const float* xn = x + (size_t)n * Cin * H * W;

#pragma unroll UNR
    for (int ci = 0; ci < Cin; ++ci) {
        const float* xc  = xn + (size_t)ci * (H * W);
        const float* xrA = xc + (size_t)iyAc * W;
        const float* xrB = xc + (size_t)iyBc * W;
        float a0 = (vA && c0) ? xrA[j0]     : 0.0f;
        float a1 =  vA        ? xrA[t0]     : 0.0f;
        float a2 =  vA        ? xrA[t0 + 1] : 0.0f;
        float a3 = (vA && c3) ? xrA[j3]     : 0.0f;
        float b0 = (vB && c0) ? xrB[j0]     : 0.0f;
        float b1 =  vB        ? xrB[t0]     : 0.0f;
        float b2 =  vB        ? xrB[t0 + 1] : 0.0f;
        float b3 = (vB && c3) ? xrB[j3]     : 0.0f;

        const float* wci = w + ((size_t)ci * Cout + co0) * 16;
#pragma unroll
        for (int o = 0; o < COT; ++o) {
            const float* wr = wci + (size_t)o * 16;
            float wA0 = wr[p * 4 + 0], wA1 = wr[p * 4 + 1];
            float wA2 = wr[p * 4 + 2], wA3 = wr[p * 4 + 3];
            float wB0 = wr[(p + 2) * 4 + 0], wB1 = wr[(p + 2) * 4 + 1];
            float wB2 = wr[(p + 2) * 4 + 2], wB3 = wr[(p + 2) * 4 + 3];
            acc[o][0] = fmaf(a1, wA1, acc[o][0]); acc[o][0] = fmaf(a0, wA3, acc[o][0]);
            acc[o][0] = fmaf(b1, wB1, acc[o][0]); acc[o][0] = fmaf(b0, wB3, acc[o][0]);
            acc[o][1] = fmaf(a2, wA0, acc[o][1]); acc[o][1] = fmaf(a1, wA2, acc[o][1]);
            acc[o][1] = fmaf(b2, wB0, acc[o][1]); acc[o][1] = fmaf(b1, wB2, acc[o][1]);
            acc[o][2] = fmaf(a2, wA1, acc[o][2]); acc[o][2] = fmaf(a1, wA3, acc[o][2]);
            acc[o][2] = fmaf(b2, wB1, acc[o][2]); acc[o][2] = fmaf(b1, wB3, acc[o][2]);
            acc[o][3] = fmaf(a3, wA0, acc[o][3]); acc[o][3] = fmaf(a2, wA2, acc[o][3]);
            acc[o][3] = fmaf(b3, wB0, acc[o][3]); acc[o][3] = fmaf(b2, wB2, acc[o][3]);
        }
    }

    int ox0 = ox4 * 4;
#pragma unroll
    for (int o = 0; o < COT; ++o) {
        float* yr = y + (((size_t)n * Cout + co0 + o) * OH + oy) * OW + ox0;
#pragma unroll
        for (int j = 0; j < 4; ++j) {
            float v = acc[o][j];
            yr[j] = (ACT == 0) ? fmaxf(v, 0.0f) : tanhf(v);
        }
    }
}

// =============================== quantizer =================================
__global__ void __launch_bounds__(256) embed_norms(
    const float* __restrict__ embed, float* __restrict__ norms)
{
    int c = blockIdx.x * 256 + threadIdx.x;
    const float* e = embed + (size_t)c * 512;
    float s = 0.0f;
    for (int k = 0; k < 512; ++k) s = fmaf(e[k], e[k], s);
    norms[c] = s;
}

__global__ void __launch_bounds__(256, 4) vq_argmin8v(
    const float* __restrict__ z, const float* __restrict__ et,
    const float* __restrict__ norms, int* __restrict__ out)
{
    constexpr int ZS = 516;
    int row0 = blockIdx.x * 8;
    int n    = row0 >> 8;
    int yx0  = row0 & 255;
    int tid  = threadIdx.x;

    __shared__ float zr[8 * ZS];

    const float* zn = z + ((size_t)n * 512) * 256;
#pragma unroll
    for (int it = 0; it < 4; ++it) {
        int i  = tid + 256 * it;
        int rq = i & 1, kc = i >> 1;
        float4 v = *(const float4*)&zn[(size_t)kc * 256 + yx0 + 4 * rq];
        zr[(4 * rq + 0) * ZS + kc] = v.x;
        zr[(4 * rq + 1) * ZS + kc] = v.y;
        zr[(4 * rq + 2) * ZS + kc] = v.z;
        zr[(4 * rq + 3) * ZS + kc] = v.w;
    }
    __syncthreads();

    f32x4 acc[8];
#pragma unroll
    for (int r = 0; r < 8; ++r) acc[r] = (f32x4){0.f, 0.f, 0.f, 0.f};

    const float* ebase = et + 4 * tid;
    f32x4 ev[4], fv[4];
#pragma unroll
    for (int j = 0; j < 4; ++j)
        ev[j] = *(const f32x4*)&ebase[(size_t)j * 1024];

#pragma unroll 1
    for (int k4 = 0; k4 < 128; ++k4) {
        int kn = (k4 + 1 < 128) ? k4 + 1 : 127;
#pragma unroll
        for (int j = 0; j < 4; ++j)
            fv[j] = *(const f32x4*)&ebase[(size_t)(4 * kn + j) * 1024];
#pragma unroll
        for (int r = 0; r < 8; ++r) {
            float4 zz = *(const float4*)&zr[r * ZS + 4 * k4];
            f32x4 a = acc[r];
            a += ev[0] * zz.x;
            a += ev[1] * zz.y;
            a += ev[2] * zz.z;
            a += ev[3] * zz.w;
            acc[r] = a;
        }
#pragma unroll
        for (int j = 0; j < 4; ++j) ev[j] = fv[j];
    }

    float4 nb = *(const float4*)&norms[4 * tid];
    float best[8]; int bi[8];
#pragma unroll
    for (int r = 0; r < 8; ++r) {
        float d0 = nb.x - 2.0f * acc[r][0];
        float d1 = nb.y - 2.0f * acc[r][1];
        float d2 = nb.z - 2.0f * acc[r][2];
        float d3 = nb.w - 2.0f * acc[r][3];
        float b = d0; int ix = 4 * tid;
        if (d1 < b) { b = d1; ix = 4 * tid + 1; }
        if (d2 < b) { b = d2; ix = 4 * tid + 2; }
        if (d3 < b) { b = d3; ix = 4 * tid + 3; }
        best[r] = b; bi[r] = ix;
    }

    __syncthreads();
    float* rbd = zr;
    int*   rbi = (int*)(zr + 2048);
#pragma unroll
    for (int r = 0; r < 8; ++r) {
        rbd[r * 256 + tid] = best[r];
        rbi[r * 256 + tid] = bi[r];
    }
    __syncthreads();
    for (int s = 128; s > 0; s >>= 1) {
        if (tid < s) {
#pragma unroll
            for (int r = 0; r < 8; ++r) {
                int i0 = r * 256 + tid;
                float od = rbd[i0 + s]; int oi = rbi[i0 + s];
                float md = rbd[i0];     int mi = rbi[i0];
                if (od < md || (od == md && oi < mi)) { rbd[i0] = od; rbi[i0] = oi; }
            }
        }
        __syncthreads();
    }
    if (tid < 8) out[row0 + tid] = rbi[tid * 256];
}

__global__ void __launch_bounds__(256) vq_gather_pack(
    const int* __restrict__ vidx, const float* __restrict__ embed,
    unsigned* __restrict__ zq)
{
    int i = blockIdx.x * 256 + threadIdx.x;
    int yx = i & 255;
    int t  = i >> 8;
    int c  = t & 511;
    int n  = t >> 9;
    int row = (n << 8) + yx;
    zq[i] = pack_split(embed[(size_t)vidx[row] * 512 + c]);
}

// ================================ launch ===================================
extern "C" void kernel_launch(void* const* d_in, const int* in_sizes, int n_in,
                              void* d_out, int out_size, void* d_ws, size_t ws_size,
                              hipStream_t stream)
{
    (void)in_sizes; (void)n_in; (void)out_size; (void)ws_size;
    const float* x     = (const float*)d_in[0];
    const float* ew1   = (const float*)d_in[1];
    const float* eb1   = (const float*)d_in[2];
    const float* ew2   = (const float*)d_in[3];
    const float* eb2   = (const float*)d_in[4];
    const float* ew3   = (const float*)d_in[5];
    const float* eb3   = (const float*)d_in[6];
    const float* ew4   = (const float*)d_in[7];
    const float* eb4   = (const float*)d_in[8];
    const float* dw1   = (const float*)d_in[9];
    const float* db1   = (const float*)d_in[10];
    const float* dw2   = (const float*)d_in[11];
    const float* db2   = (const float*)d_in[12];
    const float* dw3   = (const float*)d_in[13];
    const float* db3   = (const float*)d_in[14];
    const float* dw4   = (const float*)d_in[15];
    const float* db4   = (const float*)d_in[16];
    const float* embed = (const float*)d_in[17];
    float* out = (float*)d_out;

    // ---- workspace layout (u32 units). Identical to R18.
    unsigned* W0   = (unsigned*)d_ws;
    unsigned* h1p  = W0;
    unsigned* h2p  = W0 + 33554432;
    unsigned* xp1  = W0 + 33554432;
    unsigned* h3p  = W0;
    float*    z    = (float*)(W0 + 8388608);
    unsigned* zq   = W0 + 12582912;
    float*    P0   = (float*)(W0 + 16777216);
    float*    P1   = (float*)(W0 + 20971520);
    int*      vidx = (int*)(W0 + 29360128);
    float*    norms= (float*)(W0 + 29368320);
    float*    g3o  = (float*)h2p;

    // packed weights + transposed codebook live in d_out until g4 overwrites
    unsigned* wp2 = (unsigned*)d_out;             // 131,072
    unsigned* wp3 = wp2 + 131072;                 // 524,288
    unsigned* wp4 = wp2 + 655360;                 // 2,097,152
    unsigned* wq1 = wp2 + 2752512;                // 1,048,576
    unsigned* wq2 = wq1 + 1048576;                // 131,072
    unsigned* wq3 = wq2 + 131072;                 // 32,768
    float*    et  = (float*)(wq3 + 32768);        // 524,288 (512x1024)
    unsigned* wp1 = (unsigned*)(et + 524288);     // 4,096 (64x64 padded)

    dim3 b256(256);

    // ---- pre-pass ----
    pack_tensor<<<dim3(512),  b256, 0, stream>>>(ew2, wp2, 131072);
    pack_tensor<<<dim3(2048), b256, 0, stream>>>(ew3, wp3, 524288);
    pack_tensor<<<dim3(8192), b256, 0, stream>>>(ew4, wp4, 2097152);
    pack_w1<<<dim3(16), b256, 0, stream>>>(ew1, wp1);
    pack_tensor<<<dim3(24576), b256, 0, stream>>>(x, xp1, 6291456);
    repack_wt_planes<512, 128><<<dim3(4096), b256, 0, stream>>>(dw1, wq1);
    repack_wt_planes<128,  64><<<dim3(512),  b256, 0, stream>>>(dw2, wq2);
    repack_wt_planes< 64,  32><<<dim3(128),  b256, 0, stream>>>(dw3, wq3);
    embed_transpose<<<dim3(2048), b256, 0, stream>>>(embed, et);

    // ---- encoder ----
    conv4s2_mfma_g<4, 3, 256, 256, 64, 4, 1, 1><<<dim3(8192), b256, 0, stream>>>(
        xp1, wp1, eb1, (float*)h1p);                       // h1 (packed)
    conv4s2_mfma<64, 128, 128, 128, 128, 1><<<dim3(2048), b256, 0, stream>>>(
        h1p, wp2, eb2, (float*)h2p);                       // h2 (packed)
    conv4s2_mfma<128, 64, 64, 256, 128, 1><<<dim3(1024), b256, 0, stream>>>(
        h2p, wp3, eb3, (float*)h3p);                       // h3 (packed)
    conv4s2_mfma<256, 32, 32, 512, 64, 0><<<dim3(1024), b256, 0, stream>>>(
        h3p, wp4, eb4, z);                                 // z (fp32)

    // ---- quantizer ----
    embed_norms<<<dim3(4), b256, 0, stream>>>(embed, norms);
    vq_argmin8v<<<dim3(1024), b256, 0, stream>>>(z, et, norms, vidx);
    vq_gather_pack<<<dim3(16384), b256, 0, stream>>>(vidx, embed, zq);

    // ---- decoder (MFMA parity-GEMM convT) ----
    convt4s2_mfma<512, 16, 16, 128, 4, 2, 1><<<dim3(4 * 128), b256, 0, stream>>>(
        zq, wq1, db1, P0);                                 // P0 (packed)
    convt4s2_mfma<128, 32, 32, 64, 4, 1, 1><<<dim3(4 * 512), b256, 0, stream>>>(
        (const unsigned*)P0, wq2, db2, P1);                // P1 (packed)
    convt4s2_mfma<64, 64, 64, 32, 2, 1, 0><<<dim3(4 * 2048), b256, 0, stream>>>(
        (const unsigned*)P1, wq3, db3, g3o);               // g3o (fp32)
    convt4s2_k<32, 128, 128, 3, 3, 1, 2><<<dim3(2048), b256, 0, stream>>>(
        g3o, dw4, db4, out);                               // tanh -> d_out
}